// Round 4
// baseline (618.794 us; speedup 1.0000x reference)
//
#include <hip/hip_runtime.h>
#include <hip/hip_bf16.h>
#include <math.h>

#define BB   4
#define SS   2048
#define EE   256
#define HH   8
#define DD   32
#define WW   33
#define KKN  (SS - WW + 1)   // 2016
#define SCALE 0.17677669529663687f  // 1/sqrt(32)
#define FMAX 20.0f           // fixed softmax max: p = exp(s - FMAX); cancels in p/l
#define SCALE2 0.25503486f           // SCALE * log2(e)
#define FM2    28.853900817779268f   // FMAX  * log2(e)

typedef __attribute__((ext_vector_type(8))) short short8v;   // 8 bf16 MFMA A/B frag
typedef __attribute__((ext_vector_type(4))) short short4v;
typedef __attribute__((ext_vector_type(4))) float float4v;   // MFMA C/D frag

// f32 -> bf16 via the compiler's HW convert path (RNE on ROCm>=7).
__device__ __forceinline__ short f2bf(float f) {
    union { __hip_bfloat16 h; short s; } c;
    c.h = __float2bfloat16(f);
    return c.s;
}

// paired convert: one v_cvt_pk_bf16_f32 for two floats (compiler API, no asm)
__device__ __forceinline__ short2 f2bf2(float a, float b) {
    union { __hip_bfloat162 h; short2 s; } c;
    float2 f; f.x = a; f.y = b;
    c.h = __float22bfloat162_rn(f);
    return c.s;
}

#if __has_builtin(__builtin_amdgcn_exp2f)
__device__ __forceinline__ float exp2_fast(float x) { return __builtin_amdgcn_exp2f(x); }
#else
__device__ __forceinline__ float exp2_fast(float x) { return __expf(x * 0.6931471805599453f); }
#endif

// ---------------------------------------------------------------------------
// Kernel 1: QKV projection as LDS-tiled GEMM (unchanged).
// ---------------------------------------------------------------------------
__global__ __launch_bounds__(256) void qkv_kernel(
    const float* __restrict__ x,
    const float* __restrict__ Wq, const float* __restrict__ bq,
    const float* __restrict__ Wk, const float* __restrict__ bk,
    const float* __restrict__ Wv, const float* __restrict__ bv,
    short* __restrict__ qo, short* __restrict__ ko, float* __restrict__ vo)
{
    __shared__ alignas(16) float xs[64][68];
    __shared__ alignas(16) float ws[64][68];

    const int t   = threadIdx.x;
    const int r0  = blockIdx.x * 64;
    const int ct  = blockIdx.y;
    const int mat = ct >> 2;
    const int cm0 = (ct & 3) * 64;
    const float* Wm   = (mat == 0) ? Wq : (mat == 1) ? Wk : Wv;
    const float* bias = (mat == 0) ? bq : (mat == 1) ? bk : bv;

    const int tr = t >> 4, tc = t & 15;

    float acc[4][4];
#pragma unroll
    for (int i = 0; i < 4; i++)
#pragma unroll
        for (int j = 0; j < 4; j++) acc[i][j] = 0.f;

    for (int ec = 0; ec < 4; ec++) {
        const int e0 = ec * 64;
        __syncthreads();
#pragma unroll
        for (int i = 0; i < 4; i++) {
            int L = t + i * 256;
            int r = L >> 4, c4 = (L & 15) * 4;
            *(float4*)&xs[r][c4] = *(const float4*)(x  + (size_t)(r0 + r) * EE + e0 + c4);
            *(float4*)&ws[r][c4] = *(const float4*)(Wm + (size_t)(e0 + r) * EE + cm0 + c4);
        }
        __syncthreads();

#pragma unroll
        for (int eg = 0; eg < 16; eg++) {
            float4 xv[4], wv4[4];
#pragma unroll
            for (int i = 0; i < 4; i++) xv[i]  = *(const float4*)&xs[tr * 4 + i][eg * 4];
#pragma unroll
            for (int j = 0; j < 4; j++) wv4[j] = *(const float4*)&ws[eg * 4 + j][tc * 4];
            const float* w0p = (const float*)&wv4[0];
            const float* w1p = (const float*)&wv4[1];
            const float* w2p = (const float*)&wv4[2];
            const float* w3p = (const float*)&wv4[3];
#pragma unroll
            for (int i = 0; i < 4; i++)
#pragma unroll
                for (int j = 0; j < 4; j++)
                    acc[i][j] = acc[i][j] + xv[i].x * w0p[j] + xv[i].y * w1p[j]
                                          + xv[i].z * w2p[j] + xv[i].w * w3p[j];
        }
    }

    const int cmb = cm0 + tc * 4;
    const int h = cmb >> 5, d0 = cmb & 31;
    float b4[4];
#pragma unroll
    for (int j = 0; j < 4; j++) b4[j] = bias[cmb + j];

#pragma unroll
    for (int i = 0; i < 4; i++) {
        int row = r0 + tr * 4 + i;
        int b_  = row >> 11;
        int s   = row & 2047;
        size_t o = (((size_t)(b_ * HH + h)) * SS + s) * DD + d0;
        if (mat == 2) {
            float4 vv;
            vv.x = acc[i][0] + b4[0]; vv.y = acc[i][1] + b4[1];
            vv.z = acc[i][2] + b4[2]; vv.w = acc[i][3] + b4[3];
            *(float4*)(vo + o) = vv;
        } else {
            short4v sv;
            sv.x = f2bf(acc[i][0] + b4[0]); sv.y = f2bf(acc[i][1] + b4[1]);
            sv.z = f2bf(acc[i][2] + b4[2]); sv.w = f2bf(acc[i][3] + b4[3]);
            *(short4v*)(((mat == 0) ? qo : ko) + o) = sv;
        }
    }
}

// ---------------------------------------------------------------------------
// Kernel 2: sliding-window sum of V -> transposed bf16 vsT[bh][d][kk].
//   (R12 grid: 64-thread blocks, 1024 blocks.)
// ---------------------------------------------------------------------------
__global__ __launch_bounds__(64) void vs_kernel(
    const float* __restrict__ v, short* __restrict__ vsT)
{
    const int t   = threadIdx.x;
    const int d4  = t & 7;
    const int kkb = blockIdx.x * 8 + (t >> 3);
    const int bh  = blockIdx.y;
    if (kkb >= 252) return;
    const int kb0 = kkb * 8;

    const float4* vp = (const float4*)(v + ((size_t)bh * SS + kb0) * DD) + d4;
    float4 rbuf[7];
    float4 acc = {0.f, 0.f, 0.f, 0.f};
#pragma unroll
    for (int w = 0; w < WW; w++) {
        float4 xv = vp[w * 8];
        if (w < 7) rbuf[w] = xv;
        acc.x += xv.x; acc.y += xv.y; acc.z += xv.z; acc.w += xv.w;
    }
    short8v sh[4];
    sh[0][0] = f2bf(acc.x); sh[1][0] = f2bf(acc.y);
    sh[2][0] = f2bf(acc.z); sh[3][0] = f2bf(acc.w);
#pragma unroll
    for (int s = 1; s < 8; s++) {
        float4 sub = rbuf[s - 1];
        float4 add = vp[(s + 32) * 8];
        acc.x += add.x - sub.x; acc.y += add.y - sub.y;
        acc.z += add.z - sub.z; acc.w += add.w - sub.w;
        sh[0][s] = f2bf(acc.x); sh[1][s] = f2bf(acc.y);
        sh[2][s] = f2bf(acc.z); sh[3][s] = f2bf(acc.w);
    }
#pragma unroll
    for (int j = 0; j < 4; j++) {
        short* op = vsT + ((size_t)bh * DD + 4 * d4 + j) * KKN + kb0;
        *(short8v*)op = sh[j];
    }
}

// ---------------------------------------------------------------------------
// Kernel 3: flash attention, BK=64 keys/iter (32 iters, 2 barriers each).
//   R13 changes (occupancy 4 -> 5 blocks/CU; LDS 38528 -> 31360 B):
//   - Kb ring 128 -> 96 rows, mod-96 addressing via incremental scalar
//     k0m in {0,64,32} + one conditional subtract. Window(kt) = rows
//     [64kt, 64kt+96); B(kt) prefetches rows [64kt+96, 64kt+160) into the
//     slots of rows [64kt, 64kt+64) which die after phase A(kt).
//   - vT single-buffered [32][72] with T14 split staging: global->reg loads
//     issued at phase-A top (tile kt + Kb prefetch rows), reg->LDS writes at
//     phase-B top. Write(B(kt)) vs PV-read(A(kt)) guarded by barrier A;
//     read(A(kt+1)) guarded by barrier B.
//   - __launch_bounds__(256, 5).
//   - All strides remain multiples of 8 shorts (16B) for ds_*_b128 alignment.
// ---------------------------------------------------------------------------
__global__ __launch_bounds__(256, 5) void attn_kernel(
    const short* __restrict__ qg, const short* __restrict__ kg,
    const short* __restrict__ vsTg, float* __restrict__ out)
{
    __shared__ alignas(16) short QbS[64][40];      // Qext; pb union after hoist
    __shared__ alignas(16) short Kb[96][40];       // 96-row K ring (mod 96)
    __shared__ alignas(16) short Gst[96][72];      // bf16 skewed Gram (row 95 = junk)
    __shared__ alignas(16) short vT[32][72];       // single-buffered vs tile [d][ki]
    __shared__ float lrow[32];

    short (*Qb)[40] = QbS;
    short (*pb)[72] = (short (*)[72])QbS;   // 32*72 shorts <= 64*40 ✓ (cols 64..71 junk)

    const int t  = threadIdx.x;
    const int qt = blockIdx.x;
    const int bh = blockIdx.y;
    const int q0 = qt * 32;

    const short* qb   = qg   + (size_t)bh * SS * DD;
    const short* kb   = kg   + (size_t)bh * SS * DD;
    const short* vsTb = vsTg + (size_t)bh * DD * KKN;

    const int lane = t & 63, wv = t >> 6;
    const int quad = lane >> 4, lr = lane & 15;
    const int ptm = wv >> 1, ptn = wv & 1;
    const int jcol = 64 + (t & 7);            // junk column for clamped score writes

    const int qitw  = wv & 1;                 // this wave's qit (score ownership)
    const int tbase = wv >> 1;                // tile parity for this wave pair
    const int qi    = qitw * 16 + lr;         // score row, constant per lane

    const int vd  = t >> 3, vc8 = (t & 7) * 8;   // vT stage coords (kt-invariant)
    const int r2  = t >> 2, c8r = (t & 3) * 8;   // Kb stage coords (kt-invariant)

    // ---- zero-init Gst (garbage containment; unwritten cells stay 0) ----
    {
        short8v z = {0, 0, 0, 0, 0, 0, 0, 0};
        short* g = &Gst[0][0];
        for (int i = t; i < 864; i += 256) *(short8v*)(g + 8 * i) = z;
    }

    // ---- initial staging: Qext 64 rows + K rows 0..95 ----
    {
        int gq = q0 - 16 + r2;
        if (gq >= 0 && gq < SS) {
            *(short8v*)&Qb[r2][c8r] = *(const short8v*)(qb + (size_t)gq * DD + c8r);
        } else {
            float4 z = {0.f, 0.f, 0.f, 0.f};
            *(float4*)&Qb[r2][c8r] = z;
        }
        *(short8v*)&Kb[r2][c8r] = *(const short8v*)(kb + (size_t)r2 * DD + c8r);
        if (t < 128)
            *(short8v*)&Kb[64 + r2][c8r] = *(const short8v*)(kb + (size_t)(64 + r2) * DD + c8r);
    }
    if (t < 32) lrow[t] = 0.f;
    __syncthreads();

    // ---- hoist loop-invariant Q B-frags (Qb dead afterwards) ----
    short8v Qf[4];
#pragma unroll
    for (int tq = 0; tq < 4; tq++)
        Qf[tq] = *(const short8v*)&Qb[tq * 16 + lr][quad * 8];

    // ---- banded-ones U-frags for this wave's qit: U[m][qi]=1 iff qi<=m<=qi+32
    short8v Ufw[2];
#pragma unroll
    for (int ch = 0; ch < 2; ch++) {
        short8v u;
#pragma unroll
        for (int j = 0; j < 8; j++) {
            int m = ch * 32 + quad * 8 + j;
            u[j] = (qi <= m && m <= qi + 32) ? (short)0x3F80 : (short)0;
        }
        Ufw[ch] = u;
    }

    float4v acc = {0.f, 0.f, 0.f, 0.f};
    float lsumw = 0.f;
    const int npass = (wv < 2) ? 2 : 1;
    int k0m = 0;                              // k0 mod 96, cycle {0,64,32}

    for (int kt = 0; kt < 32; kt++) {
        const int k0 = kt * 64;
        // ================= Phase A =================
        // T14 issue-early: global->reg loads (vs tile kt; Kb rows k0+96..159)
        short8v vstage;
        {
            int col = k0 + vc8; if (col > KKN - 8) col = KKN - 8;
            vstage = *(const short8v*)(vsTb + (size_t)vd * KKN + col);
        }
        short8v kstage;
        if (kt < 31) {
            int gp = k0 + 96 + r2;
            int ga = (gp < SS) ? gp : (SS - 1);
            kstage = *(const short8v*)(kb + (size_t)ga * DD + c8r);
        }

        // Gram MFMA: wave wv owns K-tiles tk = wv (+4); B = Qf[tq]
        for (int pass = 0; pass < npass; pass++) {
            const int tk = wv + pass * 4;
            int krow = k0m + tk * 16 + lr; if (krow >= 96) krow -= 96;
            const short8v A = *(const short8v*)&Kb[krow][quad * 8];
#pragma unroll
            for (int tq = 0; tq < 4; tq++) {
                const int del = tk - tq;
                if (del < -2 || del > 4) continue;   // dead tile
                float4v c0 = {0.f, 0.f, 0.f, 0.f};
                c0 = __builtin_amdgcn_mfma_f32_16x16x32_bf16(A, Qf[tq], c0, 0, 0, 0);
                const int i   = tq * 16 + lr;
                const int j2b = tk * 16 + quad * 4 - i + 31;
                short* gbase = &Gst[0][i];
                short2 g01 = f2bf2(c0[0], c0[1]);
                short2 g23 = f2bf2(c0[2], c0[3]);
                short gv[4] = {g01.x, g01.y, g23.x, g23.y};
#pragma unroll
                for (int e = 0; e < 4; e++) {
                    int j2 = j2b + e;
                    short* dst = ((unsigned)j2 < 95u) ? (gbase + j2 * 72)
                                                      : (gbase + 95 * 72);
                    *dst = gv[e];
                }
            }
        }

        // PV for PREVIOUS iter (k = 64: 2 chained MFMAs), vT single buffer
        if (kt > 0) {
            const short8v Ap0 = *(const short8v*)&pb[ptm * 16 + lr][quad * 8];
            const short8v Ap1 = *(const short8v*)&pb[ptm * 16 + lr][32 + quad * 8];
            const short8v Bv0 = *(const short8v*)&vT[ptn * 16 + lr][quad * 8];
            const short8v Bv1 = *(const short8v*)&vT[ptn * 16 + lr][32 + quad * 8];
            __builtin_amdgcn_s_setprio(1);
            acc = __builtin_amdgcn_mfma_f32_16x16x32_bf16(Ap0, Bv0, acc, 0, 0, 0);
            acc = __builtin_amdgcn_mfma_f32_16x16x32_bf16(Ap1, Bv1, acc, 0, 0, 0);
            __builtin_amdgcn_s_setprio(0);
        }
        __syncthreads();   // [A] Gst complete; Kb/pb/vT consumed

        // ================= Phase B =================
        // T14 write-late: staged regs -> LDS
        *(short8v*)&vT[vd][vc8] = vstage;
        if (kt < 31) {
            int slot = k0m + r2; if (slot >= 96) slot -= 96;
            *(short8v*)&Kb[slot][c8r] = kstage;
        }

        // KKN tail: last tile covers keys 1984..2015 only (ki < 32).
        const unsigned lim = (kt == 31) ? 32u : 64u;
        if (kt == 31) {
            short4v z4 = {0, 0, 0, 0};
            int zr = t >> 3, zc = (t & 7) * 4 + 32;
            *(short4v*)&pb[zr][zc] = z4;
        }

        // scores: 3 (tile,qit)-units per wave; qit = qitw fixed.
        short* prow = &pb[qi][0];
#pragma unroll
        for (int u = 0; u < 3; u++) {
            const int tile = 2 * u + tbase;      // wv<2: {0,2,4}; wv>=2: {1,3,5}
            const int jrow = tile * 16 + lr;
            const short8v A0f = *(const short8v*)&Gst[jrow][quad * 8];
            const short8v A1f = *(const short8v*)&Gst[jrow][32 + quad * 8];
            float4v D = {0.f, 0.f, 0.f, 0.f};
            __builtin_amdgcn_s_setprio(1);
            D = __builtin_amdgcn_mfma_f32_16x16x32_bf16(A0f, Ufw[0], D, 0, 0, 0);
            D = __builtin_amdgcn_mfma_f32_16x16x32_bf16(A1f, Ufw[1], D, 0, 0, 0);
            __builtin_amdgcn_s_setprio(0);
            const int kib = qi + tile * 16 + quad * 4 - 31;
            float p0 = exp2_fast(fmaf(D[0], SCALE2, -FM2));
            float p1 = exp2_fast(fmaf(D[1], SCALE2, -FM2));
            float p2 = exp2_fast(fmaf(D[2], SCALE2, -FM2));
            float p3 = exp2_fast(fmaf(D[3], SCALE2, -FM2));
            short2 c01 = f2bf2(p0, p1);
            short2 c23 = f2bf2(p2, p3);
            float pv[4] = {p0, p1, p2, p3};
            short cv[4] = {c01.x, c01.y, c23.x, c23.y};
#pragma unroll
            for (int e = 0; e < 4; e++) {
                int ki = kib + e;
                bool ok = (unsigned)ki < lim;
                short* dst = ok ? (prow + ki) : (prow + jcol);
                *dst = cv[e];
                lsumw += ok ? pv[e] : 0.f;
            }
        }
        __syncthreads();   // [B] pb ready; vT/Kb staged writes visible
        k0m += 64; if (k0m >= 96) k0m -= 96;
    }

    // ---- final PV (kt = 31 tile, staged at B(31)) ----
    {
        const short8v Ap0 = *(const short8v*)&pb[ptm * 16 + lr][quad * 8];
        const short8v Ap1 = *(const short8v*)&pb[ptm * 16 + lr][32 + quad * 8];
        const short8v Bv0 = *(const short8v*)&vT[ptn * 16 + lr][quad * 8];
        const short8v Bv1 = *(const short8v*)&vT[ptn * 16 + lr][32 + quad * 8];
        acc = __builtin_amdgcn_mfma_f32_16x16x32_bf16(Ap0, Bv0, acc, 0, 0, 0);
        acc = __builtin_amdgcn_mfma_f32_16x16x32_bf16(Ap1, Bv1, acc, 0, 0, 0);
    }

    // ---- l reduction: cross-quad shuffle then one atomic per wave ----
    {
        float s = lsumw;
        s += __shfl_xor(s, 16);
        s += __shfl_xor(s, 32);
        if (quad == 0) atomicAdd(&lrow[qitw * 16 + lr], s);
    }
    __syncthreads();

    // ---- epilogue ----
    {
        const int rrow = ptm * 16 + quad * 4;
        const int col  = ptn * 16 + lr;
        const int b_ = bh >> 3, h = bh & 7;
#pragma unroll
        for (int e = 0; e < 4; e++) {
            int s_ = q0 + rrow + e;
            out[((size_t)(b_ * SS + s_)) * EE + h * DD + col] = acc[e] / lrow[rrow + e];
        }
    }
}

// ---------------------------------------------------------------------------
extern "C" void kernel_launch(void* const* d_in, const int* in_sizes, int n_in,
                              void* d_out, int out_size, void* d_ws, size_t ws_size,
                              hipStream_t stream)
{
    (void)in_sizes; (void)n_in; (void)out_size; (void)ws_size;
    const float* x  = (const float*)d_in[0];
    const float* Wq = (const float*)d_in[1];
    const float* bq = (const float*)d_in[2];
    const float* Wk = (const float*)d_in[3];
    const float* bk = (const float*)d_in[4];
    const float* Wv = (const float*)d_in[5];
    const float* bv = (const float*)d_in[6];
    float* out = (float*)d_out;

    const size_t REG = (size_t)BB * HH * SS * DD;   // 2,097,152
    short* qbf   = (short*)d_ws;
    short* kbf   = qbf + REG;
    float* vbuf  = (float*)(kbf + REG);
    short* vsTb  = (short*)(vbuf + REG);            // 32*32*2016 shorts

    qkv_kernel<<<dim3(128, 12), dim3(256), 0, stream>>>(x, Wq, bq, Wk, bk, Wv, bv,
                                                        qbf, kbf, vbuf);
    vs_kernel<<<dim3(32, 32), dim3(64), 0, stream>>>(vbuf, vsTb);
    attn_kernel<<<dim3(64, 32), dim3(256), 0, stream>>>(qbf, kbf, vsTb, out);
}

// Round 5
// 275.832 us; speedup vs baseline: 2.2434x; 2.2434x over previous
//
#include <hip/hip_runtime.h>
#include <hip/hip_bf16.h>
#include <math.h>

#define BB   4
#define SS   2048
#define EE   256
#define HH   8
#define DD   32
#define WW   33
#define KKN  (SS - WW + 1)   // 2016
#define SCALE 0.17677669529663687f  // 1/sqrt(32)
#define FMAX 20.0f           // fixed softmax max: p = exp(s - FMAX); cancels in p/l
#define SCALE2 0.25503486f           // SCALE * log2(e)
#define FM2    28.853900817779268f   // FMAX  * log2(e)

typedef __attribute__((ext_vector_type(8))) short short8v;   // 8 bf16 MFMA A/B frag
typedef __attribute__((ext_vector_type(4))) short short4v;
typedef __attribute__((ext_vector_type(4))) float float4v;   // MFMA C/D frag

// f32 -> bf16 via the compiler's HW convert path (RNE on ROCm>=7).
__device__ __forceinline__ short f2bf(float f) {
    union { __hip_bfloat16 h; short s; } c;
    c.h = __float2bfloat16(f);
    return c.s;
}

// paired convert: one v_cvt_pk_bf16_f32 for two floats (compiler API, no asm)
__device__ __forceinline__ short2 f2bf2(float a, float b) {
    union { __hip_bfloat162 h; short2 s; } c;
    float2 f; f.x = a; f.y = b;
    c.h = __float22bfloat162_rn(f);
    return c.s;
}

#if __has_builtin(__builtin_amdgcn_exp2f)
__device__ __forceinline__ float exp2_fast(float x) { return __builtin_amdgcn_exp2f(x); }
#else
__device__ __forceinline__ float exp2_fast(float x) { return __expf(x * 0.6931471805599453f); }
#endif

// ---------------------------------------------------------------------------
// Kernel 1: QKV projection as LDS-tiled GEMM (unchanged).
// ---------------------------------------------------------------------------
__global__ __launch_bounds__(256) void qkv_kernel(
    const float* __restrict__ x,
    const float* __restrict__ Wq, const float* __restrict__ bq,
    const float* __restrict__ Wk, const float* __restrict__ bk,
    const float* __restrict__ Wv, const float* __restrict__ bv,
    short* __restrict__ qo, short* __restrict__ ko, float* __restrict__ vo)
{
    __shared__ alignas(16) float xs[64][68];
    __shared__ alignas(16) float ws[64][68];

    const int t   = threadIdx.x;
    const int r0  = blockIdx.x * 64;
    const int ct  = blockIdx.y;
    const int mat = ct >> 2;
    const int cm0 = (ct & 3) * 64;
    const float* Wm   = (mat == 0) ? Wq : (mat == 1) ? Wk : Wv;
    const float* bias = (mat == 0) ? bq : (mat == 1) ? bk : bv;

    const int tr = t >> 4, tc = t & 15;

    float acc[4][4];
#pragma unroll
    for (int i = 0; i < 4; i++)
#pragma unroll
        for (int j = 0; j < 4; j++) acc[i][j] = 0.f;

    for (int ec = 0; ec < 4; ec++) {
        const int e0 = ec * 64;
        __syncthreads();
#pragma unroll
        for (int i = 0; i < 4; i++) {
            int L = t + i * 256;
            int r = L >> 4, c4 = (L & 15) * 4;
            *(float4*)&xs[r][c4] = *(const float4*)(x  + (size_t)(r0 + r) * EE + e0 + c4);
            *(float4*)&ws[r][c4] = *(const float4*)(Wm + (size_t)(e0 + r) * EE + cm0 + c4);
        }
        __syncthreads();

#pragma unroll
        for (int eg = 0; eg < 16; eg++) {
            float4 xv[4], wv4[4];
#pragma unroll
            for (int i = 0; i < 4; i++) xv[i]  = *(const float4*)&xs[tr * 4 + i][eg * 4];
#pragma unroll
            for (int j = 0; j < 4; j++) wv4[j] = *(const float4*)&ws[eg * 4 + j][tc * 4];
            const float* w0p = (const float*)&wv4[0];
            const float* w1p = (const float*)&wv4[1];
            const float* w2p = (const float*)&wv4[2];
            const float* w3p = (const float*)&wv4[3];
#pragma unroll
            for (int i = 0; i < 4; i++)
#pragma unroll
                for (int j = 0; j < 4; j++)
                    acc[i][j] = acc[i][j] + xv[i].x * w0p[j] + xv[i].y * w1p[j]
                                          + xv[i].z * w2p[j] + xv[i].w * w3p[j];
        }
    }

    const int cmb = cm0 + tc * 4;
    const int h = cmb >> 5, d0 = cmb & 31;
    float b4[4];
#pragma unroll
    for (int j = 0; j < 4; j++) b4[j] = bias[cmb + j];

#pragma unroll
    for (int i = 0; i < 4; i++) {
        int row = r0 + tr * 4 + i;
        int b_  = row >> 11;
        int s   = row & 2047;
        size_t o = (((size_t)(b_ * HH + h)) * SS + s) * DD + d0;
        if (mat == 2) {
            float4 vv;
            vv.x = acc[i][0] + b4[0]; vv.y = acc[i][1] + b4[1];
            vv.z = acc[i][2] + b4[2]; vv.w = acc[i][3] + b4[3];
            *(float4*)(vo + o) = vv;
        } else {
            short4v sv;
            sv.x = f2bf(acc[i][0] + b4[0]); sv.y = f2bf(acc[i][1] + b4[1]);
            sv.z = f2bf(acc[i][2] + b4[2]); sv.w = f2bf(acc[i][3] + b4[3]);
            *(short4v*)(((mat == 0) ? qo : ko) + o) = sv;
        }
    }
}

// ---------------------------------------------------------------------------
// Kernel 2: sliding-window sum of V -> transposed bf16 vsT[bh][d][kk].
//   (64-thread blocks, 1024 blocks.)
// ---------------------------------------------------------------------------
__global__ __launch_bounds__(64) void vs_kernel(
    const float* __restrict__ v, short* __restrict__ vsT)
{
    const int t   = threadIdx.x;
    const int d4  = t & 7;
    const int kkb = blockIdx.x * 8 + (t >> 3);
    const int bh  = blockIdx.y;
    if (kkb >= 252) return;
    const int kb0 = kkb * 8;

    const float4* vp = (const float4*)(v + ((size_t)bh * SS + kb0) * DD) + d4;
    float4 rbuf[7];
    float4 acc = {0.f, 0.f, 0.f, 0.f};
#pragma unroll
    for (int w = 0; w < WW; w++) {
        float4 xv = vp[w * 8];
        if (w < 7) rbuf[w] = xv;
        acc.x += xv.x; acc.y += xv.y; acc.z += xv.z; acc.w += xv.w;
    }
    short8v sh[4];
    sh[0][0] = f2bf(acc.x); sh[1][0] = f2bf(acc.y);
    sh[2][0] = f2bf(acc.z); sh[3][0] = f2bf(acc.w);
#pragma unroll
    for (int s = 1; s < 8; s++) {
        float4 sub = rbuf[s - 1];
        float4 add = vp[(s + 32) * 8];
        acc.x += add.x - sub.x; acc.y += add.y - sub.y;
        acc.z += add.z - sub.z; acc.w += add.w - sub.w;
        sh[0][s] = f2bf(acc.x); sh[1][s] = f2bf(acc.y);
        sh[2][s] = f2bf(acc.z); sh[3][s] = f2bf(acc.w);
    }
#pragma unroll
    for (int j = 0; j < 4; j++) {
        short* op = vsT + ((size_t)bh * DD + 4 * d4 + j) * KKN + kb0;
        *(short8v*)op = sh[j];
    }
}

// ---------------------------------------------------------------------------
// Kernel 3: flash attention, BK=64 keys/iter (32 iters, 2 barriers each).
//   R14 (= R12 staging mechanism + R13 LDS layout):
//   - Kb ring 96 rows (mod-96 via incremental k0m in {0,64,32}); B(kt)
//     direct global->LDS prefetch of rows [64kt+96, 64kt+160) into the slots
//     of rows [64kt, 64kt+64) which died after A(kt). Verified on HW in R13.
//   - vT single-buffered [32][72]: direct global->LDS stage of tile kt at
//     B(kt) top; read by PV at A(kt+1) (barrier B between); overwrite of
//     tile kt-1 guarded by barrier A. Final PV reads tile 31 (staged B(31)).
//   - NO cross-barrier register staging (R13's spill -> L2-thrash disaster:
//     FETCH 37->428 MB). All loads short-lived, drained at the same-phase
//     barrier.
//   - LDS total 31360 B -> 5 blocks/CU (LDS-limited); launch_bounds(256,4)
//     unchanged from R12 (VGPR ~64 allows 5 blocks).
// ---------------------------------------------------------------------------
__global__ __launch_bounds__(256, 4) void attn_kernel(
    const short* __restrict__ qg, const short* __restrict__ kg,
    const short* __restrict__ vsTg, float* __restrict__ out)
{
    __shared__ alignas(16) short QbS[64][40];      // Qext; pb union after hoist
    __shared__ alignas(16) short Kb[96][40];       // 96-row K ring (mod 96)
    __shared__ alignas(16) short Gst[96][72];      // bf16 skewed Gram (row 95 = junk)
    __shared__ alignas(16) short vT[32][72];       // single-buffered vs tile [d][ki]
    __shared__ float lrow[32];

    short (*Qb)[40] = QbS;
    short (*pb)[72] = (short (*)[72])QbS;   // 32*72 shorts <= 64*40 ✓ (cols 64..71 junk)

    const int t  = threadIdx.x;
    const int qt = blockIdx.x;
    const int bh = blockIdx.y;
    const int q0 = qt * 32;

    const short* qb   = qg   + (size_t)bh * SS * DD;
    const short* kb   = kg   + (size_t)bh * SS * DD;
    const short* vsTb = vsTg + (size_t)bh * DD * KKN;

    const int lane = t & 63, wv = t >> 6;
    const int quad = lane >> 4, lr = lane & 15;
    const int ptm = wv >> 1, ptn = wv & 1;
    const int jcol = 64 + (t & 7);            // junk column for clamped score writes

    const int qitw  = wv & 1;                 // this wave's qit (score ownership)
    const int tbase = wv >> 1;                // tile parity for this wave pair
    const int qi    = qitw * 16 + lr;         // score row, constant per lane

    const int vd  = t >> 3, vc8 = (t & 7) * 8;   // vT stage coords (kt-invariant)
    const int r2  = t >> 2, c8r = (t & 3) * 8;   // Kb stage coords (kt-invariant)

    // ---- zero-init Gst (garbage containment; unwritten cells stay 0) ----
    {
        short8v z = {0, 0, 0, 0, 0, 0, 0, 0};
        short* g = &Gst[0][0];
        for (int i = t; i < 864; i += 256) *(short8v*)(g + 8 * i) = z;
    }

    // ---- initial staging: Qext 64 rows + K rows 0..95 + vT tile 0 ----
    {
        int gq = q0 - 16 + r2;
        if (gq >= 0 && gq < SS) {
            *(short8v*)&Qb[r2][c8r] = *(const short8v*)(qb + (size_t)gq * DD + c8r);
        } else {
            float4 z = {0.f, 0.f, 0.f, 0.f};
            *(float4*)&Qb[r2][c8r] = z;
        }
        *(short8v*)&Kb[r2][c8r] = *(const short8v*)(kb + (size_t)r2 * DD + c8r);
        if (t < 128)
            *(short8v*)&Kb[64 + r2][c8r] = *(const short8v*)(kb + (size_t)(64 + r2) * DD + c8r);
    }
    if (t < 32) lrow[t] = 0.f;
    __syncthreads();

    // ---- hoist loop-invariant Q B-frags (Qb dead afterwards) ----
    short8v Qf[4];
#pragma unroll
    for (int tq = 0; tq < 4; tq++)
        Qf[tq] = *(const short8v*)&Qb[tq * 16 + lr][quad * 8];

    // ---- banded-ones U-frags for this wave's qit: U[m][qi]=1 iff qi<=m<=qi+32
    short8v Ufw[2];
#pragma unroll
    for (int ch = 0; ch < 2; ch++) {
        short8v u;
#pragma unroll
        for (int j = 0; j < 8; j++) {
            int m = ch * 32 + quad * 8 + j;
            u[j] = (qi <= m && m <= qi + 32) ? (short)0x3F80 : (short)0;
        }
        Ufw[ch] = u;
    }

    float4v acc = {0.f, 0.f, 0.f, 0.f};
    float lsumw = 0.f;
    const int npass = (wv < 2) ? 2 : 1;
    int k0m = 0;                              // k0 mod 96, cycle {0,64,32}

    for (int kt = 0; kt < 32; kt++) {
        const int k0 = kt * 64;
        // ================= Phase A =================
        // Gram MFMA: wave wv owns K-tiles tk = wv (+4); B = Qf[tq]
        for (int pass = 0; pass < npass; pass++) {
            const int tk = wv + pass * 4;
            int krow = k0m + tk * 16 + lr; if (krow >= 96) krow -= 96;
            const short8v A = *(const short8v*)&Kb[krow][quad * 8];
#pragma unroll
            for (int tq = 0; tq < 4; tq++) {
                const int del = tk - tq;
                if (del < -2 || del > 4) continue;   // dead tile
                float4v c0 = {0.f, 0.f, 0.f, 0.f};
                c0 = __builtin_amdgcn_mfma_f32_16x16x32_bf16(A, Qf[tq], c0, 0, 0, 0);
                const int i   = tq * 16 + lr;
                const int j2b = tk * 16 + quad * 4 - i + 31;
                short* gbase = &Gst[0][i];
                short2 g01 = f2bf2(c0[0], c0[1]);
                short2 g23 = f2bf2(c0[2], c0[3]);
                short gv[4] = {g01.x, g01.y, g23.x, g23.y};
#pragma unroll
                for (int e = 0; e < 4; e++) {
                    int j2 = j2b + e;
                    short* dst = ((unsigned)j2 < 95u) ? (gbase + j2 * 72)
                                                      : (gbase + 95 * 72);
                    *dst = gv[e];
                }
            }
        }

        // PV for PREVIOUS iter (k = 64: 2 chained MFMAs); vT holds tile kt-1
        if (kt > 0) {
            const short8v Ap0 = *(const short8v*)&pb[ptm * 16 + lr][quad * 8];
            const short8v Ap1 = *(const short8v*)&pb[ptm * 16 + lr][32 + quad * 8];
            const short8v Bv0 = *(const short8v*)&vT[ptn * 16 + lr][quad * 8];
            const short8v Bv1 = *(const short8v*)&vT[ptn * 16 + lr][32 + quad * 8];
            __builtin_amdgcn_s_setprio(1);
            acc = __builtin_amdgcn_mfma_f32_16x16x32_bf16(Ap0, Bv0, acc, 0, 0, 0);
            acc = __builtin_amdgcn_mfma_f32_16x16x32_bf16(Ap1, Bv1, acc, 0, 0, 0);
            __builtin_amdgcn_s_setprio(0);
        }
        __syncthreads();   // [A] Gst complete; Kb old rows / pb / vT consumed

        // ================= Phase B =================
        // direct global->LDS staging (short-lived regs, drained at barrier B):
        // vT <- vs tile kt (clamped 16B-aligned tail)
        {
            int col = k0 + vc8; if (col > KKN - 8) col = KKN - 8;
            *(short8v*)&vT[vd][vc8] = *(const short8v*)(vsTb + (size_t)vd * KKN + col);
        }
        // Kb ring prefetch: rows k0+96 .. k0+159 into dead slots (clamped addr)
        if (kt < 31) {
            int gp = k0 + 96 + r2;
            int ga = (gp < SS) ? gp : (SS - 1);
            int slot = k0m + r2; if (slot >= 96) slot -= 96;
            *(short8v*)&Kb[slot][c8r] = *(const short8v*)(kb + (size_t)ga * DD + c8r);
        }

        // KKN tail: last tile covers keys 1984..2015 only (ki < 32).
        const unsigned lim = (kt == 31) ? 32u : 64u;
        if (kt == 31) {
            short4v z4 = {0, 0, 0, 0};
            int zr = t >> 3, zc = (t & 7) * 4 + 32;
            *(short4v*)&pb[zr][zc] = z4;
        }

        // scores: 3 (tile,qit)-units per wave; qit = qitw fixed.
        short* prow = &pb[qi][0];
#pragma unroll
        for (int u = 0; u < 3; u++) {
            const int tile = 2 * u + tbase;      // wv<2: {0,2,4}; wv>=2: {1,3,5}
            const int jrow = tile * 16 + lr;
            const short8v A0f = *(const short8v*)&Gst[jrow][quad * 8];
            const short8v A1f = *(const short8v*)&Gst[jrow][32 + quad * 8];
            float4v D = {0.f, 0.f, 0.f, 0.f};
            __builtin_amdgcn_s_setprio(1);
            D = __builtin_amdgcn_mfma_f32_16x16x32_bf16(A0f, Ufw[0], D, 0, 0, 0);
            D = __builtin_amdgcn_mfma_f32_16x16x32_bf16(A1f, Ufw[1], D, 0, 0, 0);
            __builtin_amdgcn_s_setprio(0);
            const int kib = qi + tile * 16 + quad * 4 - 31;
            float p0 = exp2_fast(fmaf(D[0], SCALE2, -FM2));
            float p1 = exp2_fast(fmaf(D[1], SCALE2, -FM2));
            float p2 = exp2_fast(fmaf(D[2], SCALE2, -FM2));
            float p3 = exp2_fast(fmaf(D[3], SCALE2, -FM2));
            short2 c01 = f2bf2(p0, p1);
            short2 c23 = f2bf2(p2, p3);
            float pv[4] = {p0, p1, p2, p3};
            short cv[4] = {c01.x, c01.y, c23.x, c23.y};
#pragma unroll
            for (int e = 0; e < 4; e++) {
                int ki = kib + e;
                bool ok = (unsigned)ki < lim;
                short* dst = ok ? (prow + ki) : (prow + jcol);
                *dst = cv[e];
                lsumw += ok ? pv[e] : 0.f;
            }
        }
        __syncthreads();   // [B] pb ready; vT/Kb staged writes visible
        k0m += 64; if (k0m >= 96) k0m -= 96;
    }

    // ---- final PV (tile 31, staged at B(31)) ----
    {
        const short8v Ap0 = *(const short8v*)&pb[ptm * 16 + lr][quad * 8];
        const short8v Ap1 = *(const short8v*)&pb[ptm * 16 + lr][32 + quad * 8];
        const short8v Bv0 = *(const short8v*)&vT[ptn * 16 + lr][quad * 8];
        const short8v Bv1 = *(const short8v*)&vT[ptn * 16 + lr][32 + quad * 8];
        acc = __builtin_amdgcn_mfma_f32_16x16x32_bf16(Ap0, Bv0, acc, 0, 0, 0);
        acc = __builtin_amdgcn_mfma_f32_16x16x32_bf16(Ap1, Bv1, acc, 0, 0, 0);
    }

    // ---- l reduction: cross-quad shuffle then one atomic per wave ----
    {
        float s = lsumw;
        s += __shfl_xor(s, 16);
        s += __shfl_xor(s, 32);
        if (quad == 0) atomicAdd(&lrow[qitw * 16 + lr], s);
    }
    __syncthreads();

    // ---- epilogue ----
    {
        const int rrow = ptm * 16 + quad * 4;
        const int col  = ptn * 16 + lr;
        const int b_ = bh >> 3, h = bh & 7;
#pragma unroll
        for (int e = 0; e < 4; e++) {
            int s_ = q0 + rrow + e;
            out[((size_t)(b_ * SS + s_)) * EE + h * DD + col] = acc[e] / lrow[rrow + e];
        }
    }
}

// ---------------------------------------------------------------------------
extern "C" void kernel_launch(void* const* d_in, const int* in_sizes, int n_in,
                              void* d_out, int out_size, void* d_ws, size_t ws_size,
                              hipStream_t stream)
{
    (void)in_sizes; (void)n_in; (void)out_size; (void)ws_size;
    const float* x  = (const float*)d_in[0];
    const float* Wq = (const float*)d_in[1];
    const float* bq = (const float*)d_in[2];
    const float* Wk = (const float*)d_in[3];
    const float* bk = (const float*)d_in[4];
    const float* Wv = (const float*)d_in[5];
    const float* bv = (const float*)d_in[6];
    float* out = (float*)d_out;

    const size_t REG = (size_t)BB * HH * SS * DD;   // 2,097,152
    short* qbf   = (short*)d_ws;
    short* kbf   = qbf + REG;
    float* vbuf  = (float*)(kbf + REG);
    short* vsTb  = (short*)(vbuf + REG);            // 32*32*2016 shorts

    qkv_kernel<<<dim3(128, 12), dim3(256), 0, stream>>>(x, Wq, bq, Wk, bk, Wv, bv,
                                                        qbf, kbf, vbuf);
    vs_kernel<<<dim3(32, 32), dim3(64), 0, stream>>>(vbuf, vsTb);
    attn_kernel<<<dim3(64, 32), dim3(256), 0, stream>>>(qbf, kbf, vsTb, out);
}

// Round 8
// 262.668 us; speedup vs baseline: 2.3558x; 1.0501x over previous
//
#include <hip/hip_runtime.h>
#include <hip/hip_bf16.h>
#include <math.h>

#define BB   4
#define SS   2048
#define EE   256
#define HH   8
#define DD   32
#define WW   33
#define KKN  (SS - WW + 1)   // 2016
#define SCALE 0.17677669529663687f  // 1/sqrt(32)
#define FMAX 20.0f           // fixed softmax max: p = exp(s - FMAX); cancels in p/l
#define SCALE2 0.25503486f           // SCALE * log2(e)
#define FM2    28.853900817779268f   // FMAX  * log2(e)

typedef __attribute__((ext_vector_type(8))) short short8v;   // 8 bf16 MFMA A/B frag
typedef __attribute__((ext_vector_type(4))) short short4v;
typedef __attribute__((ext_vector_type(4))) float float4v;   // MFMA C/D frag

// f32 -> bf16 via the compiler's HW convert path (RNE on ROCm>=7).
__device__ __forceinline__ short f2bf(float f) {
    union { __hip_bfloat16 h; short s; } c;
    c.h = __float2bfloat16(f);
    return c.s;
}

// bf16 bits -> f32 (exact)
__device__ __forceinline__ float bf2f(short h) {
    union { unsigned u; float f; } c;
    c.u = ((unsigned)(unsigned short)h) << 16;
    return c.f;
}

// paired convert: one v_cvt_pk_bf16_f32 for two floats (compiler API, no asm)
__device__ __forceinline__ short2 f2bf2(float a, float b) {
    union { __hip_bfloat162 h; short2 s; } c;
    float2 f; f.x = a; f.y = b;
    c.h = __float22bfloat162_rn(f);
    return c.s;
}

#if __has_builtin(__builtin_amdgcn_exp2f)
__device__ __forceinline__ float exp2_fast(float x) { return __builtin_amdgcn_exp2f(x); }
#else
__device__ __forceinline__ float exp2_fast(float x) { return __expf(x * 0.6931471805599453f); }
#endif

// ---------------------------------------------------------------------------
// Kernel 0 (R16): hi/lo bf16 decomposition.
//   x -> xh + xl (both bf16; xl = bf16(x - float(xh)), residual exact in f32).
//   Wq/Wk -> TRANSPOSED hi/lo: wth/wtl[mat][n][k] = split(W[k][n]).
//   q = xh*wh + xh*wl + xl*wh reproduces the fp32 GEMM to ~2^-18 relative.
// ---------------------------------------------------------------------------
__global__ __launch_bounds__(256) void cvt_kernel(
    const float* __restrict__ x,
    const float* __restrict__ Wq, const float* __restrict__ Wk,
    short* __restrict__ xh, short* __restrict__ xl,
    short* __restrict__ wth, short* __restrict__ wtl)
{
    const int t  = threadIdx.x;
    const int bx = blockIdx.x;
    if (bx < 1024) {
        // x: 4*2048*256 = 2,097,152 floats; 1024 blocks * 256 thr * 8 = exact
        size_t i8 = ((size_t)bx * 256 + t) * 8;
        float4 f0 = *(const float4*)(x + i8);
        float4 f1 = *(const float4*)(x + i8 + 4);
        float f[8] = {f0.x, f0.y, f0.z, f0.w, f1.x, f1.y, f1.z, f1.w};
        short8v h, l;
#pragma unroll
        for (int j = 0; j < 8; j++) {
            short hb = f2bf(f[j]);
            h[j] = hb;
            l[j] = f2bf(f[j] - bf2f(hb));
        }
        *(short8v*)(xh + i8) = h;
        *(short8v*)(xl + i8) = l;
    } else {
        // W transpose hi/lo: 2 mats * 256*256; 64 blocks * 256 thr * 8 = exact.
        int o   = (bx - 1024) * 2048 + t * 8;
        int mat = o >> 16;
        int rem = o & 65535;
        int n = rem >> 8, k0 = rem & 255;
        const float* W = mat ? Wk : Wq;
        short8v h, l;
#pragma unroll
        for (int j = 0; j < 8; j++) {
            float f = W[(size_t)(k0 + j) * 256 + n];
            short hb = f2bf(f);
            h[j] = hb;
            l[j] = f2bf(f - bf2f(hb));
        }
        *(short8v*)(wth + o) = h;
        *(short8v*)(wtl + o) = l;
    }
}

// ---------------------------------------------------------------------------
// Kernel 1a (R16): Q/K projection as hi/lo bf16 MFMA GEMM (fp32-equivalent).
//   Block = 64 rows x 128 cols, 4 waves. Grid (128, 4): y = mat*2 + colblock.
//   K-loop: 8 steps of 32. Per ct: 3 MFMAs (ah*bh, ah*bl, al*bh).
//   Fragment/D layout copied from the HW-proven attn Gram MFMA:
//   D = mfma(A=x rows, B=W^T rows): D row = quad*4+e (x-row), col = lr (Wcol).
//   LDS 30720 B -> 5 blocks/CU. No min-wave launch bound (R13 lesson).
// ---------------------------------------------------------------------------
__global__ __launch_bounds__(256) void qk_mfma_kernel(
    const short* __restrict__ xh, const short* __restrict__ xl,
    const short* __restrict__ wth, const short* __restrict__ wtl,
    const float* __restrict__ bq, const float* __restrict__ bk,
    short* __restrict__ qo, short* __restrict__ ko)
{
    __shared__ alignas(16) short xsh[64][40];    // x hi tile  [row][k]
    __shared__ alignas(16) short xsl[64][40];    // x lo tile
    __shared__ alignas(16) short wsh[128][40];   // W^T hi tile [col][k]
    __shared__ alignas(16) short wsl[128][40];   // W^T lo tile

    const int t   = threadIdx.x;
    const int r0  = blockIdx.x * 64;
    const int mat = blockIdx.y >> 1;
    const int cb  = blockIdx.y & 1;
    const int lane = t & 63, wv = t >> 6;
    const int quad = lane >> 4, lr = lane & 15;
    const float* bias = mat ? bk : bq;
    short* op = mat ? ko : qo;
    const size_t wofs = (size_t)(mat * 256 + cb * 128) * 256;
    const short* wthm = wth + wofs;
    const short* wtlm = wtl + wofs;

    float4v acc[8];
#pragma unroll
    for (int ct = 0; ct < 8; ct++) acc[ct] = (float4v){0.f, 0.f, 0.f, 0.f};

    for (int kk = 0; kk < 8; kk++) {
        __syncthreads();
        // stage x hi/lo: 64 rows x 32 k = 256 chunks each, 1/thread
        {
            int r = t >> 2, c8 = (t & 3) * 8;
            size_t go = (size_t)(r0 + r) * 256 + kk * 32 + c8;
            *(short8v*)&xsh[r][c8] = *(const short8v*)(xh + go);
            *(short8v*)&xsl[r][c8] = *(const short8v*)(xl + go);
        }
        // stage W^T hi/lo: 128 rows x 32 k = 512 chunks each, 2/thread
#pragma unroll
        for (int i = 0; i < 2; i++) {
            int L = t + i * 256;
            int wr = L >> 2, c8 = (L & 3) * 8;
            size_t go = (size_t)wr * 256 + kk * 32 + c8;
            *(short8v*)&wsh[wr][c8] = *(const short8v*)(wthm + go);
            *(short8v*)&wsl[wr][c8] = *(const short8v*)(wtlm + go);
        }
        __syncthreads();

        const short8v ah = *(const short8v*)&xsh[wv * 16 + lr][quad * 8];
        const short8v al = *(const short8v*)&xsl[wv * 16 + lr][quad * 8];
#pragma unroll
        for (int ct = 0; ct < 8; ct++) {
            const short8v bh_ = *(const short8v*)&wsh[ct * 16 + lr][quad * 8];
            const short8v bl_ = *(const short8v*)&wsl[ct * 16 + lr][quad * 8];
            acc[ct] = __builtin_amdgcn_mfma_f32_16x16x32_bf16(ah, bh_, acc[ct], 0, 0, 0);
            acc[ct] = __builtin_amdgcn_mfma_f32_16x16x32_bf16(ah, bl_, acc[ct], 0, 0, 0);
            acc[ct] = __builtin_amdgcn_mfma_f32_16x16x32_bf16(al, bh_, acc[ct], 0, 0, 0);
        }
    }

    // epilogue: D row = r0 + wv*16 + quad*4 + e; col = cb*128 + ct*16 + lr
#pragma unroll
    for (int ct = 0; ct < 8; ct++) {
        int col = cb * 128 + ct * 16 + lr;
        float bv_ = bias[col];
        int h = col >> 5, d = col & 31;
#pragma unroll
        for (int e = 0; e < 4; e++) {
            int row = r0 + wv * 16 + quad * 4 + e;
            int b_ = row >> 11, s = row & 2047;
            size_t o = (((size_t)(b_ * HH + h)) * SS + s) * DD + d;
            op[o] = f2bf(acc[ct][e] + bv_);
        }
    }
}

// ---------------------------------------------------------------------------
// Kernel 1b: V projection, fp32 LDS-tiled GEMM (exact; V enters out linearly).
//   Launched with ct0=8 -> mat==2 only.
// ---------------------------------------------------------------------------
__global__ __launch_bounds__(256) void qkv_kernel(
    const float* __restrict__ x,
    const float* __restrict__ Wq, const float* __restrict__ bq,
    const float* __restrict__ Wk, const float* __restrict__ bk,
    const float* __restrict__ Wv, const float* __restrict__ bv,
    short* __restrict__ qo, short* __restrict__ ko, float* __restrict__ vo,
    int ct0)
{
    __shared__ alignas(16) float xs[64][68];
    __shared__ alignas(16) float ws[64][68];

    const int t   = threadIdx.x;
    const int r0  = blockIdx.x * 64;
    const int ct  = blockIdx.y + ct0;
    const int mat = ct >> 2;
    const int cm0 = (ct & 3) * 64;
    const float* Wm   = (mat == 0) ? Wq : (mat == 1) ? Wk : Wv;
    const float* bias = (mat == 0) ? bq : (mat == 1) ? bk : bv;

    const int tr = t >> 4, tc = t & 15;

    float acc[4][4];
#pragma unroll
    for (int i = 0; i < 4; i++)
#pragma unroll
        for (int j = 0; j < 4; j++) acc[i][j] = 0.f;

    for (int ec = 0; ec < 4; ec++) {
        const int e0 = ec * 64;
        __syncthreads();
#pragma unroll
        for (int i = 0; i < 4; i++) {
            int L = t + i * 256;
            int r = L >> 4, c4 = (L & 15) * 4;
            *(float4*)&xs[r][c4] = *(const float4*)(x  + (size_t)(r0 + r) * EE + e0 + c4);
            *(float4*)&ws[r][c4] = *(const float4*)(Wm + (size_t)(e0 + r) * EE + cm0 + c4);
        }
        __syncthreads();

#pragma unroll
        for (int eg = 0; eg < 16; eg++) {
            float4 xv[4], wv4[4];
#pragma unroll
            for (int i = 0; i < 4; i++) xv[i]  = *(const float4*)&xs[tr * 4 + i][eg * 4];
#pragma unroll
            for (int j = 0; j < 4; j++) wv4[j] = *(const float4*)&ws[eg * 4 + j][tc * 4];
            const float* w0p = (const float*)&wv4[0];
            const float* w1p = (const float*)&wv4[1];
            const float* w2p = (const float*)&wv4[2];
            const float* w3p = (const float*)&wv4[3];
#pragma unroll
            for (int i = 0; i < 4; i++)
#pragma unroll
                for (int j = 0; j < 4; j++)
                    acc[i][j] = acc[i][j] + xv[i].x * w0p[j] + xv[i].y * w1p[j]
                                          + xv[i].z * w2p[j] + xv[i].w * w3p[j];
        }
    }

    const int cmb = cm0 + tc * 4;
    const int h = cmb >> 5, d0 = cmb & 31;
    float b4[4];
#pragma unroll
    for (int j = 0; j < 4; j++) b4[j] = bias[cmb + j];

#pragma unroll
    for (int i = 0; i < 4; i++) {
        int row = r0 + tr * 4 + i;
        int b_  = row >> 11;
        int s   = row & 2047;
        size_t o = (((size_t)(b_ * HH + h)) * SS + s) * DD + d0;
        if (mat == 2) {
            float4 vv;
            vv.x = acc[i][0] + b4[0]; vv.y = acc[i][1] + b4[1];
            vv.z = acc[i][2] + b4[2]; vv.w = acc[i][3] + b4[3];
            *(float4*)(vo + o) = vv;
        } else {
            short4v sv;
            sv.x = f2bf(acc[i][0] + b4[0]); sv.y = f2bf(acc[i][1] + b4[1]);
            sv.z = f2bf(acc[i][2] + b4[2]); sv.w = f2bf(acc[i][3] + b4[3]);
            *(short4v*)(((mat == 0) ? qo : ko) + o) = sv;
        }
    }
}

// ---------------------------------------------------------------------------
// Kernel 2: sliding-window sum of V -> transposed bf16 vsT[bh][d][kk].
// ---------------------------------------------------------------------------
__global__ __launch_bounds__(64) void vs_kernel(
    const float* __restrict__ v, short* __restrict__ vsT)
{
    const int t   = threadIdx.x;
    const int d4  = t & 7;
    const int kkb = blockIdx.x * 8 + (t >> 3);
    const int bh  = blockIdx.y;
    if (kkb >= 252) return;
    const int kb0 = kkb * 8;

    const float4* vp = (const float4*)(v + ((size_t)bh * SS + kb0) * DD) + d4;
    float4 rbuf[7];
    float4 acc = {0.f, 0.f, 0.f, 0.f};
#pragma unroll
    for (int w = 0; w < WW; w++) {
        float4 xv = vp[w * 8];
        if (w < 7) rbuf[w] = xv;
        acc.x += xv.x; acc.y += xv.y; acc.z += xv.z; acc.w += xv.w;
    }
    short8v sh[4];
    sh[0][0] = f2bf(acc.x); sh[1][0] = f2bf(acc.y);
    sh[2][0] = f2bf(acc.z); sh[3][0] = f2bf(acc.w);
#pragma unroll
    for (int s = 1; s < 8; s++) {
        float4 sub = rbuf[s - 1];
        float4 add = vp[(s + 32) * 8];
        acc.x += add.x - sub.x; acc.y += add.y - sub.y;
        acc.z += add.z - sub.z; acc.w += add.w - sub.w;
        sh[0][s] = f2bf(acc.x); sh[1][s] = f2bf(acc.y);
        sh[2][s] = f2bf(acc.z); sh[3][s] = f2bf(acc.w);
    }
#pragma unroll
    for (int j = 0; j < 4; j++) {
        short* op = vsT + ((size_t)bh * DD + 4 * d4 + j) * KKN + kb0;
        *(short8v*)op = sh[j];
    }
}

// ---------------------------------------------------------------------------
// Kernel 3: flash attention — UNCHANGED R14 (proven 172 us, absmax 0.5).
// ---------------------------------------------------------------------------
__global__ __launch_bounds__(256, 4) void attn_kernel(
    const short* __restrict__ qg, const short* __restrict__ kg,
    const short* __restrict__ vsTg, float* __restrict__ out)
{
    __shared__ alignas(16) short QbS[64][40];      // Qext; pb union after hoist
    __shared__ alignas(16) short Kb[96][40];       // 96-row K ring (mod 96)
    __shared__ alignas(16) short Gst[96][72];      // bf16 skewed Gram (row 95 = junk)
    __shared__ alignas(16) short vT[32][72];       // single-buffered vs tile [d][ki]
    __shared__ float lrow[32];

    short (*Qb)[40] = QbS;
    short (*pb)[72] = (short (*)[72])QbS;   // 32*72 shorts <= 64*40 ✓ (cols 64..71 junk)

    const int t  = threadIdx.x;
    const int qt = blockIdx.x;
    const int bh = blockIdx.y;
    const int q0 = qt * 32;

    const short* qb   = qg   + (size_t)bh * SS * DD;
    const short* kb   = kg   + (size_t)bh * SS * DD;
    const short* vsTb = vsTg + (size_t)bh * DD * KKN;

    const int lane = t & 63, wv = t >> 6;
    const int quad = lane >> 4, lr = lane & 15;
    const int ptm = wv >> 1, ptn = wv & 1;
    const int jcol = 64 + (t & 7);            // junk column for clamped score writes

    const int qitw  = wv & 1;                 // this wave's qit (score ownership)
    const int tbase = wv >> 1;                // tile parity for this wave pair
    const int qi    = qitw * 16 + lr;         // score row, constant per lane

    const int vd  = t >> 3, vc8 = (t & 7) * 8;   // vT stage coords (kt-invariant)
    const int r2  = t >> 2, c8r = (t & 3) * 8;   // Kb stage coords (kt-invariant)

    // ---- zero-init Gst (garbage containment; unwritten cells stay 0) ----
    {
        short8v z = {0, 0, 0, 0, 0, 0, 0, 0};
        short* g = &Gst[0][0];
        for (int i = t; i < 864; i += 256) *(short8v*)(g + 8 * i) = z;
    }

    // ---- initial staging: Qext 64 rows + K rows 0..95 ----
    {
        int gq = q0 - 16 + r2;
        if (gq >= 0 && gq < SS) {
            *(short8v*)&Qb[r2][c8r] = *(const short8v*)(qb + (size_t)gq * DD + c8r);
        } else {
            float4 z = {0.f, 0.f, 0.f, 0.f};
            *(float4*)&Qb[r2][c8r] = z;
        }
        *(short8v*)&Kb[r2][c8r] = *(const short8v*)(kb + (size_t)r2 * DD + c8r);
        if (t < 128)
            *(short8v*)&Kb[64 + r2][c8r] = *(const short8v*)(kb + (size_t)(64 + r2) * DD + c8r);
    }
    if (t < 32) lrow[t] = 0.f;
    __syncthreads();

    // ---- hoist loop-invariant Q B-frags (Qb dead afterwards) ----
    short8v Qf[4];
#pragma unroll
    for (int tq = 0; tq < 4; tq++)
        Qf[tq] = *(const short8v*)&Qb[tq * 16 + lr][quad * 8];

    // ---- banded-ones U-frags for this wave's qit: U[m][qi]=1 iff qi<=m<=qi+32
    short8v Ufw[2];
#pragma unroll
    for (int ch = 0; ch < 2; ch++) {
        short8v u;
#pragma unroll
        for (int j = 0; j < 8; j++) {
            int m = ch * 32 + quad * 8 + j;
            u[j] = (qi <= m && m <= qi + 32) ? (short)0x3F80 : (short)0;
        }
        Ufw[ch] = u;
    }

    float4v acc = {0.f, 0.f, 0.f, 0.f};
    float lsumw = 0.f;
    const int npass = (wv < 2) ? 2 : 1;
    int k0m = 0;                              // k0 mod 96, cycle {0,64,32}

    for (int kt = 0; kt < 32; kt++) {
        const int k0 = kt * 64;
        // ================= Phase A =================
        // Gram MFMA: wave wv owns K-tiles tk = wv (+4); B = Qf[tq]
        for (int pass = 0; pass < npass; pass++) {
            const int tk = wv + pass * 4;
            int krow = k0m + tk * 16 + lr; if (krow >= 96) krow -= 96;
            const short8v A = *(const short8v*)&Kb[krow][quad * 8];
#pragma unroll
            for (int tq = 0; tq < 4; tq++) {
                const int del = tk - tq;
                if (del < -2 || del > 4) continue;   // dead tile
                float4v c0 = {0.f, 0.f, 0.f, 0.f};
                c0 = __builtin_amdgcn_mfma_f32_16x16x32_bf16(A, Qf[tq], c0, 0, 0, 0);
                const int i   = tq * 16 + lr;
                const int j2b = tk * 16 + quad * 4 - i + 31;
                short* gbase = &Gst[0][i];
                short2 g01 = f2bf2(c0[0], c0[1]);
                short2 g23 = f2bf2(c0[2], c0[3]);
                short gv[4] = {g01.x, g01.y, g23.x, g23.y};
#pragma unroll
                for (int e = 0; e < 4; e++) {
                    int j2 = j2b + e;
                    short* dst = ((unsigned)j2 < 95u) ? (gbase + j2 * 72)
                                                      : (gbase + 95 * 72);
                    *dst = gv[e];
                }
            }
        }

        // PV for PREVIOUS iter (k = 64: 2 chained MFMAs); vT holds tile kt-1
        if (kt > 0) {
            const short8v Ap0 = *(const short8v*)&pb[ptm * 16 + lr][quad * 8];
            const short8v Ap1 = *(const short8v*)&pb[ptm * 16 + lr][32 + quad * 8];
            const short8v Bv0 = *(const short8v*)&vT[ptn * 16 + lr][quad * 8];
            const short8v Bv1 = *(const short8v*)&vT[ptn * 16 + lr][32 + quad * 8];
            __builtin_amdgcn_s_setprio(1);
            acc = __builtin_amdgcn_mfma_f32_16x16x32_bf16(Ap0, Bv0, acc, 0, 0, 0);
            acc = __builtin_amdgcn_mfma_f32_16x16x32_bf16(Ap1, Bv1, acc, 0, 0, 0);
            __builtin_amdgcn_s_setprio(0);
        }
        __syncthreads();   // [A] Gst complete; Kb old rows / pb / vT consumed

        // ================= Phase B =================
        // direct global->LDS staging (short-lived regs, drained at barrier B):
        // vT <- vs tile kt (clamped 16B-aligned tail)
        {
            int col = k0 + vc8; if (col > KKN - 8) col = KKN - 8;
            *(short8v*)&vT[vd][vc8] = *(const short8v*)(vsTb + (size_t)vd * KKN + col);
        }
        // Kb ring prefetch: rows k0+96 .. k0+159 into dead slots (clamped addr)
        if (kt < 31) {
            int gp = k0 + 96 + r2;
            int ga = (gp < SS) ? gp : (SS - 1);
            int slot = k0m + r2; if (slot >= 96) slot -= 96;
            *(short8v*)&Kb[slot][c8r] = *(const short8v*)(kb + (size_t)ga * DD + c8r);
        }

        // KKN tail: last tile covers keys 1984..2015 only (ki < 32).
        const unsigned lim = (kt == 31) ? 32u : 64u;
        if (kt == 31) {
            short4v z4 = {0, 0, 0, 0};
            int zr = t >> 3, zc = (t & 7) * 4 + 32;
            *(short4v*)&pb[zr][zc] = z4;
        }

        // scores: 3 (tile,qit)-units per wave; qit = qitw fixed.
        short* prow = &pb[qi][0];
#pragma unroll
        for (int u = 0; u < 3; u++) {
            const int tile = 2 * u + tbase;      // wv<2: {0,2,4}; wv>=2: {1,3,5}
            const int jrow = tile * 16 + lr;
            const short8v A0f = *(const short8v*)&Gst[jrow][quad * 8];
            const short8v A1f = *(const short8v*)&Gst[jrow][32 + quad * 8];
            float4v D = {0.f, 0.f, 0.f, 0.f};
            __builtin_amdgcn_s_setprio(1);
            D = __builtin_amdgcn_mfma_f32_16x16x32_bf16(A0f, Ufw[0], D, 0, 0, 0);
            D = __builtin_amdgcn_mfma_f32_16x16x32_bf16(A1f, Ufw[1], D, 0, 0, 0);
            __builtin_amdgcn_s_setprio(0);
            const int kib = qi + tile * 16 + quad * 4 - 31;
            float p0 = exp2_fast(fmaf(D[0], SCALE2, -FM2));
            float p1 = exp2_fast(fmaf(D[1], SCALE2, -FM2));
            float p2 = exp2_fast(fmaf(D[2], SCALE2, -FM2));
            float p3 = exp2_fast(fmaf(D[3], SCALE2, -FM2));
            short2 c01 = f2bf2(p0, p1);
            short2 c23 = f2bf2(p2, p3);
            float pv[4] = {p0, p1, p2, p3};
            short cv[4] = {c01.x, c01.y, c23.x, c23.y};
#pragma unroll
            for (int e = 0; e < 4; e++) {
                int ki = kib + e;
                bool ok = (unsigned)ki < lim;
                short* dst = ok ? (prow + ki) : (prow + jcol);
                *dst = cv[e];
                lsumw += ok ? pv[e] : 0.f;
            }
        }
        __syncthreads();   // [B] pb ready; vT/Kb staged writes visible
        k0m += 64; if (k0m >= 96) k0m -= 96;
    }

    // ---- final PV (tile 31, staged at B(31)) ----
    {
        const short8v Ap0 = *(const short8v*)&pb[ptm * 16 + lr][quad * 8];
        const short8v Ap1 = *(const short8v*)&pb[ptm * 16 + lr][32 + quad * 8];
        const short8v Bv0 = *(const short8v*)&vT[ptn * 16 + lr][quad * 8];
        const short8v Bv1 = *(const short8v*)&vT[ptn * 16 + lr][32 + quad * 8];
        acc = __builtin_amdgcn_mfma_f32_16x16x32_bf16(Ap0, Bv0, acc, 0, 0, 0);
        acc = __builtin_amdgcn_mfma_f32_16x16x32_bf16(Ap1, Bv1, acc, 0, 0, 0);
    }

    // ---- l reduction: cross-quad shuffle then one atomic per wave ----
    {
        float s = lsumw;
        s += __shfl_xor(s, 16);
        s += __shfl_xor(s, 32);
        if (quad == 0) atomicAdd(&lrow[qitw * 16 + lr], s);
    }
    __syncthreads();

    // ---- epilogue ----
    {
        const int rrow = ptm * 16 + quad * 4;
        const int col  = ptn * 16 + lr;
        const int b_ = bh >> 3, h = bh & 7;
#pragma unroll
        for (int e = 0; e < 4; e++) {
            int s_ = q0 + rrow + e;
            out[((size_t)(b_ * SS + s_)) * EE + h * DD + col] = acc[e] / lrow[rrow + e];
        }
    }
}

// ---------------------------------------------------------------------------
extern "C" void kernel_launch(void* const* d_in, const int* in_sizes, int n_in,
                              void* d_out, int out_size, void* d_ws, size_t ws_size,
                              hipStream_t stream)
{
    (void)in_sizes; (void)n_in; (void)out_size; (void)ws_size;
    const float* x  = (const float*)d_in[0];
    const float* Wq = (const float*)d_in[1];
    const float* bq = (const float*)d_in[2];
    const float* Wk = (const float*)d_in[3];
    const float* bk = (const float*)d_in[4];
    const float* Wv = (const float*)d_in[5];
    const float* bv = (const float*)d_in[6];
    float* out = (float*)d_out;

    const size_t REG = (size_t)BB * HH * SS * DD;   // 2,097,152
    short* qbf   = (short*)d_ws;
    short* kbf   = qbf + REG;
    float* vbuf  = (float*)(kbf + REG);
    short* vsTb  = (short*)(vbuf + REG);            // 32*32*2016 shorts

    // scratch in KNOWN-good regions (no workspace growth):
    //   xh/xl fill vbuf exactly (2*REG shorts = REG floats); dead before V-GEMM.
    //   wth/wtl (512 KB) live in out; attn fully overwrites out at the end.
    short* xh  = (short*)vbuf;
    short* xl  = xh + REG;
    short* wth = (short*)out;
    short* wtl = wth + 2 * 256 * 256;

    // 1) hi/lo bf16 decomposition of x and W^T
    cvt_kernel<<<dim3(1088), dim3(256), 0, stream>>>(x, Wq, Wk, xh, xl, wth, wtl);
    // 2) Q/K via hi/lo bf16 MFMA (fp32-equivalent precision)
    qk_mfma_kernel<<<dim3(128, 4), dim3(256), 0, stream>>>(xh, xl, wth, wtl,
                                                           bq, bk, qbf, kbf);
    // 3) V via exact fp32 GEMM (overwrites xh/xl region with vo)
    qkv_kernel<<<dim3(128, 4), dim3(256), 0, stream>>>(x, Wq, bq, Wk, bk, Wv, bv,
                                                       qbf, kbf, vbuf, 8);
    // 4) window sums of V
    vs_kernel<<<dim3(32, 32), dim3(64), 0, stream>>>(vbuf, vsTb);
    // 5) attention (overwrites every element of out)
    attn_kernel<<<dim3(64, 32), dim3(256), 0, stream>>>(qbf, kbf, vsTb, out);
}

// Round 9
// 249.704 us; speedup vs baseline: 2.4781x; 1.0519x over previous
//
#include <hip/hip_runtime.h>
#include <hip/hip_bf16.h>
#include <math.h>

#define BB   4
#define SS   2048
#define EE   256
#define HH   8
#define DD   32
#define WW   33
#define KKN  (SS - WW + 1)   // 2016
#define SCALE 0.17677669529663687f  // 1/sqrt(32)
#define FMAX 20.0f           // fixed softmax max: p = exp(s - FMAX); cancels in p/l
#define SCALE2 0.25503486f           // SCALE * log2(e)
#define FM2    28.853900817779268f   // FMAX  * log2(e)

typedef __attribute__((ext_vector_type(8))) short short8v;   // 8 bf16 MFMA A/B frag
typedef __attribute__((ext_vector_type(4))) short short4v;
typedef __attribute__((ext_vector_type(4))) float float4v;   // MFMA C/D frag

// f32 -> bf16 via the compiler's HW convert path (RNE on ROCm>=7).
__device__ __forceinline__ short f2bf(float f) {
    union { __hip_bfloat16 h; short s; } c;
    c.h = __float2bfloat16(f);
    return c.s;
}

// bf16 bits -> f32 (exact)
__device__ __forceinline__ float bf2f(short h) {
    union { unsigned u; float f; } c;
    c.u = ((unsigned)(unsigned short)h) << 16;
    return c.f;
}

// paired convert: one v_cvt_pk_bf16_f32 for two floats (compiler API, no asm)
__device__ __forceinline__ short2 f2bf2(float a, float b) {
    union { __hip_bfloat162 h; short2 s; } c;
    float2 f; f.x = a; f.y = b;
    c.h = __float22bfloat162_rn(f);
    return c.s;
}

#if __has_builtin(__builtin_amdgcn_exp2f)
__device__ __forceinline__ float exp2_fast(float x) { return __builtin_amdgcn_exp2f(x); }
#else
__device__ __forceinline__ float exp2_fast(float x) { return __expf(x * 0.6931471805599453f); }
#endif

// ---------------------------------------------------------------------------
// Kernel 0 (R17): W-only hi/lo transposed decomposition.
//   Wq/Wk/Wv -> wth/wtl[mat][n][k] (bf16 hi + bf16 residual lo).
//   96 blocks * 256 thr * 8 = 196,608 = 3*256*256 exact.
// ---------------------------------------------------------------------------
__global__ __launch_bounds__(256) void cvt_kernel(
    const float* __restrict__ Wq, const float* __restrict__ Wk,
    const float* __restrict__ Wv,
    short* __restrict__ wth, short* __restrict__ wtl)
{
    const int t  = threadIdx.x;
    const int bx = blockIdx.x;
    int o   = bx * 2048 + t * 8;
    int mat = o >> 16;
    int rem = o & 65535;
    int n = rem >> 8, k0 = rem & 255;
    const float* W = (mat == 0) ? Wq : (mat == 1) ? Wk : Wv;
    short8v h, l;
#pragma unroll
    for (int j = 0; j < 8; j++) {
        float f = W[(size_t)(k0 + j) * 256 + n];
        short hb = f2bf(f);
        h[j] = hb;
        l[j] = f2bf(f - bf2f(hb));
    }
    *(short8v*)(wth + o) = h;
    *(short8v*)(wtl + o) = l;
}

// ---------------------------------------------------------------------------
// Kernel 1 (R17): fused Q/K/V projection as hi/lo bf16 MFMA GEMM
//   (fp32-equivalent: acc = xh*wh + xh*wl + xl*wh; dropped xl*wl ~ 2^-16).
//   Block = 64 rows x 128 cols, 4 waves. Grid (128, 6): y = mat*2 + colblock.
//   x is split hi/lo IN-REGISTER during staging (no bf16 x round-trip).
//   K-loop: 8 steps of 32. Per ct: 3 MFMAs.
//   D layout (HW-proven in R16): row = r0 + wv*16 + quad*4 + e, col = ct*16+lr.
//   Epilogue: mat<2 -> bf16 q/k; mat==2 -> fp32 v.
//   LDS 30720 B. No min-wave launch bound (R13 lesson).
// ---------------------------------------------------------------------------
__global__ __launch_bounds__(256) void proj_kernel(
    const float* __restrict__ x,
    const short* __restrict__ wth, const short* __restrict__ wtl,
    const float* __restrict__ bq, const float* __restrict__ bk,
    const float* __restrict__ bv,
    short* __restrict__ qo, short* __restrict__ ko, float* __restrict__ vo)
{
    __shared__ alignas(16) short xsh[64][40];    // x hi tile  [row][k]
    __shared__ alignas(16) short xsl[64][40];    // x lo tile
    __shared__ alignas(16) short wsh[128][40];   // W^T hi tile [col][k]
    __shared__ alignas(16) short wsl[128][40];   // W^T lo tile

    const int t   = threadIdx.x;
    const int r0  = blockIdx.x * 64;
    const int mat = blockIdx.y >> 1;
    const int cb  = blockIdx.y & 1;
    const int lane = t & 63, wv = t >> 6;
    const int quad = lane >> 4, lr = lane & 15;
    const float* bias = (mat == 0) ? bq : (mat == 1) ? bk : bv;
    const size_t wofs = (size_t)(mat * 256 + cb * 128) * 256;
    const short* wthm = wth + wofs;
    const short* wtlm = wtl + wofs;

    float4v acc[8];
#pragma unroll
    for (int ct = 0; ct < 8; ct++) acc[ct] = (float4v){0.f, 0.f, 0.f, 0.f};

    for (int kk = 0; kk < 8; kk++) {
        __syncthreads();
        // stage x: read fp32, split hi/lo in registers (fused cvt)
        {
            int r = t >> 2, c8 = (t & 3) * 8;
            const float* xp = x + (size_t)(r0 + r) * 256 + kk * 32 + c8;
            float4 f0 = *(const float4*)xp;
            float4 f1 = *(const float4*)(xp + 4);
            float f[8] = {f0.x, f0.y, f0.z, f0.w, f1.x, f1.y, f1.z, f1.w};
            short8v h, l;
#pragma unroll
            for (int j = 0; j < 8; j++) {
                short hb = f2bf(f[j]);
                h[j] = hb;
                l[j] = f2bf(f[j] - bf2f(hb));
            }
            *(short8v*)&xsh[r][c8] = h;
            *(short8v*)&xsl[r][c8] = l;
        }
        // stage W^T hi/lo: 128 rows x 32 k = 512 chunks each, 2/thread
#pragma unroll
        for (int i = 0; i < 2; i++) {
            int L = t + i * 256;
            int wr = L >> 2, c8 = (L & 3) * 8;
            size_t go = (size_t)wr * 256 + kk * 32 + c8;
            *(short8v*)&wsh[wr][c8] = *(const short8v*)(wthm + go);
            *(short8v*)&wsl[wr][c8] = *(const short8v*)(wtlm + go);
        }
        __syncthreads();

        const short8v ah = *(const short8v*)&xsh[wv * 16 + lr][quad * 8];
        const short8v al = *(const short8v*)&xsl[wv * 16 + lr][quad * 8];
#pragma unroll
        for (int ct = 0; ct < 8; ct++) {
            const short8v bh_ = *(const short8v*)&wsh[ct * 16 + lr][quad * 8];
            const short8v bl_ = *(const short8v*)&wsl[ct * 16 + lr][quad * 8];
            acc[ct] = __builtin_amdgcn_mfma_f32_16x16x32_bf16(ah, bh_, acc[ct], 0, 0, 0);
            acc[ct] = __builtin_amdgcn_mfma_f32_16x16x32_bf16(ah, bl_, acc[ct], 0, 0, 0);
            acc[ct] = __builtin_amdgcn_mfma_f32_16x16x32_bf16(al, bh_, acc[ct], 0, 0, 0);
        }
    }

    // epilogue: D row = r0 + wv*16 + quad*4 + e; col = cb*128 + ct*16 + lr
    short* op = (mat == 0) ? qo : ko;
#pragma unroll
    for (int ct = 0; ct < 8; ct++) {
        int col = cb * 128 + ct * 16 + lr;
        float bv_ = bias[col];
        int h = col >> 5, d = col & 31;
#pragma unroll
        for (int e = 0; e < 4; e++) {
            int row = r0 + wv * 16 + quad * 4 + e;
            int b_ = row >> 11, s = row & 2047;
            size_t o = (((size_t)(b_ * HH + h)) * SS + s) * DD + d;
            if (mat == 2) vo[o] = acc[ct][e] + bv_;
            else          op[o] = f2bf(acc[ct][e] + bv_);
        }
    }
}

// ---------------------------------------------------------------------------
// Kernel 2: sliding-window sum of V -> transposed bf16 vsT[bh][d][kk].
// ---------------------------------------------------------------------------
__global__ __launch_bounds__(64) void vs_kernel(
    const float* __restrict__ v, short* __restrict__ vsT)
{
    const int t   = threadIdx.x;
    const int d4  = t & 7;
    const int kkb = blockIdx.x * 8 + (t >> 3);
    const int bh  = blockIdx.y;
    if (kkb >= 252) return;
    const int kb0 = kkb * 8;

    const float4* vp = (const float4*)(v + ((size_t)bh * SS + kb0) * DD) + d4;
    float4 rbuf[7];
    float4 acc = {0.f, 0.f, 0.f, 0.f};
#pragma unroll
    for (int w = 0; w < WW; w++) {
        float4 xv = vp[w * 8];
        if (w < 7) rbuf[w] = xv;
        acc.x += xv.x; acc.y += xv.y; acc.z += xv.z; acc.w += xv.w;
    }
    short8v sh[4];
    sh[0][0] = f2bf(acc.x); sh[1][0] = f2bf(acc.y);
    sh[2][0] = f2bf(acc.z); sh[3][0] = f2bf(acc.w);
#pragma unroll
    for (int s = 1; s < 8; s++) {
        float4 sub = rbuf[s - 1];
        float4 add = vp[(s + 32) * 8];
        acc.x += add.x - sub.x; acc.y += add.y - sub.y;
        acc.z += add.z - sub.z; acc.w += add.w - sub.w;
        sh[0][s] = f2bf(acc.x); sh[1][s] = f2bf(acc.y);
        sh[2][s] = f2bf(acc.z); sh[3][s] = f2bf(acc.w);
    }
#pragma unroll
    for (int j = 0; j < 4; j++) {
        short* op = vsT + ((size_t)bh * DD + 4 * d4 + j) * KKN + kb0;
        *(short8v*)op = sh[j];
    }
}

// ---------------------------------------------------------------------------
// Kernel 3: flash attention — UNCHANGED R14 (proven 170 us, absmax 0.44).
// ---------------------------------------------------------------------------
__global__ __launch_bounds__(256, 4) void attn_kernel(
    const short* __restrict__ qg, const short* __restrict__ kg,
    const short* __restrict__ vsTg, float* __restrict__ out)
{
    __shared__ alignas(16) short QbS[64][40];      // Qext; pb union after hoist
    __shared__ alignas(16) short Kb[96][40];       // 96-row K ring (mod 96)
    __shared__ alignas(16) short Gst[96][72];      // bf16 skewed Gram (row 95 = junk)
    __shared__ alignas(16) short vT[32][72];       // single-buffered vs tile [d][ki]
    __shared__ float lrow[32];

    short (*Qb)[40] = QbS;
    short (*pb)[72] = (short (*)[72])QbS;   // 32*72 shorts <= 64*40 ✓ (cols 64..71 junk)

    const int t  = threadIdx.x;
    const int qt = blockIdx.x;
    const int bh = blockIdx.y;
    const int q0 = qt * 32;

    const short* qb   = qg   + (size_t)bh * SS * DD;
    const short* kb   = kg   + (size_t)bh * SS * DD;
    const short* vsTb = vsTg + (size_t)bh * DD * KKN;

    const int lane = t & 63, wv = t >> 6;
    const int quad = lane >> 4, lr = lane & 15;
    const int ptm = wv >> 1, ptn = wv & 1;
    const int jcol = 64 + (t & 7);            // junk column for clamped score writes

    const int qitw  = wv & 1;                 // this wave's qit (score ownership)
    const int tbase = wv >> 1;                // tile parity for this wave pair
    const int qi    = qitw * 16 + lr;         // score row, constant per lane

    const int vd  = t >> 3, vc8 = (t & 7) * 8;   // vT stage coords (kt-invariant)
    const int r2  = t >> 2, c8r = (t & 3) * 8;   // Kb stage coords (kt-invariant)

    // ---- zero-init Gst (garbage containment; unwritten cells stay 0) ----
    {
        short8v z = {0, 0, 0, 0, 0, 0, 0, 0};
        short* g = &Gst[0][0];
        for (int i = t; i < 864; i += 256) *(short8v*)(g + 8 * i) = z;
    }

    // ---- initial staging: Qext 64 rows + K rows 0..95 ----
    {
        int gq = q0 - 16 + r2;
        if (gq >= 0 && gq < SS) {
            *(short8v*)&Qb[r2][c8r] = *(const short8v*)(qb + (size_t)gq * DD + c8r);
        } else {
            float4 z = {0.f, 0.f, 0.f, 0.f};
            *(float4*)&Qb[r2][c8r] = z;
        }
        *(short8v*)&Kb[r2][c8r] = *(const short8v*)(kb + (size_t)r2 * DD + c8r);
        if (t < 128)
            *(short8v*)&Kb[64 + r2][c8r] = *(const short8v*)(kb + (size_t)(64 + r2) * DD + c8r);
    }
    if (t < 32) lrow[t] = 0.f;
    __syncthreads();

    // ---- hoist loop-invariant Q B-frags (Qb dead afterwards) ----
    short8v Qf[4];
#pragma unroll
    for (int tq = 0; tq < 4; tq++)
        Qf[tq] = *(const short8v*)&Qb[tq * 16 + lr][quad * 8];

    // ---- banded-ones U-frags for this wave's qit: U[m][qi]=1 iff qi<=m<=qi+32
    short8v Ufw[2];
#pragma unroll
    for (int ch = 0; ch < 2; ch++) {
        short8v u;
#pragma unroll
        for (int j = 0; j < 8; j++) {
            int m = ch * 32 + quad * 8 + j;
            u[j] = (qi <= m && m <= qi + 32) ? (short)0x3F80 : (short)0;
        }
        Ufw[ch] = u;
    }

    float4v acc = {0.f, 0.f, 0.f, 0.f};
    float lsumw = 0.f;
    const int npass = (wv < 2) ? 2 : 1;
    int k0m = 0;                              // k0 mod 96, cycle {0,64,32}

    for (int kt = 0; kt < 32; kt++) {
        const int k0 = kt * 64;
        // ================= Phase A =================
        // Gram MFMA: wave wv owns K-tiles tk = wv (+4); B = Qf[tq]
        for (int pass = 0; pass < npass; pass++) {
            const int tk = wv + pass * 4;
            int krow = k0m + tk * 16 + lr; if (krow >= 96) krow -= 96;
            const short8v A = *(const short8v*)&Kb[krow][quad * 8];
#pragma unroll
            for (int tq = 0; tq < 4; tq++) {
                const int del = tk - tq;
                if (del < -2 || del > 4) continue;   // dead tile
                float4v c0 = {0.f, 0.f, 0.f, 0.f};
                c0 = __builtin_amdgcn_mfma_f32_16x16x32_bf16(A, Qf[tq], c0, 0, 0, 0);
                const int i   = tq * 16 + lr;
                const int j2b = tk * 16 + quad * 4 - i + 31;
                short* gbase = &Gst[0][i];
                short2 g01 = f2bf2(c0[0], c0[1]);
                short2 g23 = f2bf2(c0[2], c0[3]);
                short gv[4] = {g01.x, g01.y, g23.x, g23.y};
#pragma unroll
                for (int e = 0; e < 4; e++) {
                    int j2 = j2b + e;
                    short* dst = ((unsigned)j2 < 95u) ? (gbase + j2 * 72)
                                                      : (gbase + 95 * 72);
                    *dst = gv[e];
                }
            }
        }

        // PV for PREVIOUS iter (k = 64: 2 chained MFMAs); vT holds tile kt-1
        if (kt > 0) {
            const short8v Ap0 = *(const short8v*)&pb[ptm * 16 + lr][quad * 8];
            const short8v Ap1 = *(const short8v*)&pb[ptm * 16 + lr][32 + quad * 8];
            const short8v Bv0 = *(const short8v*)&vT[ptn * 16 + lr][quad * 8];
            const short8v Bv1 = *(const short8v*)&vT[ptn * 16 + lr][32 + quad * 8];
            __builtin_amdgcn_s_setprio(1);
            acc = __builtin_amdgcn_mfma_f32_16x16x32_bf16(Ap0, Bv0, acc, 0, 0, 0);
            acc = __builtin_amdgcn_mfma_f32_16x16x32_bf16(Ap1, Bv1, acc, 0, 0, 0);
            __builtin_amdgcn_s_setprio(0);
        }
        __syncthreads();   // [A] Gst complete; Kb old rows / pb / vT consumed

        // ================= Phase B =================
        // direct global->LDS staging (short-lived regs, drained at barrier B):
        // vT <- vs tile kt (clamped 16B-aligned tail)
        {
            int col = k0 + vc8; if (col > KKN - 8) col = KKN - 8;
            *(short8v*)&vT[vd][vc8] = *(const short8v*)(vsTb + (size_t)vd * KKN + col);
        }
        // Kb ring prefetch: rows k0+96 .. k0+159 into dead slots (clamped addr)
        if (kt < 31) {
            int gp = k0 + 96 + r2;
            int ga = (gp < SS) ? gp : (SS - 1);
            int slot = k0m + r2; if (slot >= 96) slot -= 96;
            *(short8v*)&Kb[slot][c8r] = *(const short8v*)(kb + (size_t)ga * DD + c8r);
        }

        // KKN tail: last tile covers keys 1984..2015 only (ki < 32).
        const unsigned lim = (kt == 31) ? 32u : 64u;
        if (kt == 31) {
            short4v z4 = {0, 0, 0, 0};
            int zr = t >> 3, zc = (t & 7) * 4 + 32;
            *(short4v*)&pb[zr][zc] = z4;
        }

        // scores: 3 (tile,qit)-units per wave; qit = qitw fixed.
        short* prow = &pb[qi][0];
#pragma unroll
        for (int u = 0; u < 3; u++) {
            const int tile = 2 * u + tbase;      // wv<2: {0,2,4}; wv>=2: {1,3,5}
            const int jrow = tile * 16 + lr;
            const short8v A0f = *(const short8v*)&Gst[jrow][quad * 8];
            const short8v A1f = *(const short8v*)&Gst[jrow][32 + quad * 8];
            float4v D = {0.f, 0.f, 0.f, 0.f};
            __builtin_amdgcn_s_setprio(1);
            D = __builtin_amdgcn_mfma_f32_16x16x32_bf16(A0f, Ufw[0], D, 0, 0, 0);
            D = __builtin_amdgcn_mfma_f32_16x16x32_bf16(A1f, Ufw[1], D, 0, 0, 0);
            __builtin_amdgcn_s_setprio(0);
            const int kib = qi + tile * 16 + quad * 4 - 31;
            float p0 = exp2_fast(fmaf(D[0], SCALE2, -FM2));
            float p1 = exp2_fast(fmaf(D[1], SCALE2, -FM2));
            float p2 = exp2_fast(fmaf(D[2], SCALE2, -FM2));
            float p3 = exp2_fast(fmaf(D[3], SCALE2, -FM2));
            short2 c01 = f2bf2(p0, p1);
            short2 c23 = f2bf2(p2, p3);
            float pv[4] = {p0, p1, p2, p3};
            short cv[4] = {c01.x, c01.y, c23.x, c23.y};
#pragma unroll
            for (int e = 0; e < 4; e++) {
                int ki = kib + e;
                bool ok = (unsigned)ki < lim;
                short* dst = ok ? (prow + ki) : (prow + jcol);
                *dst = cv[e];
                lsumw += ok ? pv[e] : 0.f;
            }
        }
        __syncthreads();   // [B] pb ready; vT/Kb staged writes visible
        k0m += 64; if (k0m >= 96) k0m -= 96;
    }

    // ---- final PV (tile 31, staged at B(31)) ----
    {
        const short8v Ap0 = *(const short8v*)&pb[ptm * 16 + lr][quad * 8];
        const short8v Ap1 = *(const short8v*)&pb[ptm * 16 + lr][32 + quad * 8];
        const short8v Bv0 = *(const short8v*)&vT[ptn * 16 + lr][quad * 8];
        const short8v Bv1 = *(const short8v*)&vT[ptn * 16 + lr][32 + quad * 8];
        acc = __builtin_amdgcn_mfma_f32_16x16x32_bf16(Ap0, Bv0, acc, 0, 0, 0);
        acc = __builtin_amdgcn_mfma_f32_16x16x32_bf16(Ap1, Bv1, acc, 0, 0, 0);
    }

    // ---- l reduction: cross-quad shuffle then one atomic per wave ----
    {
        float s = lsumw;
        s += __shfl_xor(s, 16);
        s += __shfl_xor(s, 32);
        if (quad == 0) atomicAdd(&lrow[qitw * 16 + lr], s);
    }
    __syncthreads();

    // ---- epilogue ----
    {
        const int rrow = ptm * 16 + quad * 4;
        const int col  = ptn * 16 + lr;
        const int b_ = bh >> 3, h = bh & 7;
#pragma unroll
        for (int e = 0; e < 4; e++) {
            int s_ = q0 + rrow + e;
            out[((size_t)(b_ * SS + s_)) * EE + h * DD + col] = acc[e] / lrow[rrow + e];
        }
    }
}

// ---------------------------------------------------------------------------
extern "C" void kernel_launch(void* const* d_in, const int* in_sizes, int n_in,
                              void* d_out, int out_size, void* d_ws, size_t ws_size,
                              hipStream_t stream)
{
    (void)in_sizes; (void)n_in; (void)out_size; (void)ws_size;
    const float* x  = (const float*)d_in[0];
    const float* Wq = (const float*)d_in[1];
    const float* bq = (const float*)d_in[2];
    const float* Wk = (const float*)d_in[3];
    const float* bk = (const float*)d_in[4];
    const float* Wv = (const float*)d_in[5];
    const float* bv = (const float*)d_in[6];
    float* out = (float*)d_out;

    const size_t REG = (size_t)BB * HH * SS * DD;   // 2,097,152
    short* qbf   = (short*)d_ws;
    short* kbf   = qbf + REG;
    float* vbuf  = (float*)(kbf + REG);
    short* vsTb  = (short*)(vbuf + REG);            // 32*32*2016 shorts

    // W^T hi/lo scratch (3 mats * 65536 shorts each = 768 KB) lives in `out`;
    // attn fully overwrites out afterwards.
    short* wth = (short*)out;
    short* wtl = wth + 3 * 256 * 256;

    // 1) hi/lo bf16 decomposition of W^T (q, k, v)
    cvt_kernel<<<dim3(96), dim3(256), 0, stream>>>(Wq, Wk, Wv, wth, wtl);
    // 2) fused Q/K/V projection via hi/lo bf16 MFMA (x split in-register)
    proj_kernel<<<dim3(128, 6), dim3(256), 0, stream>>>(x, wth, wtl,
                                                        bq, bk, bv,
                                                        qbf, kbf, vbuf);
    // 3) window sums of V
    vs_kernel<<<dim3(32, 32), dim3(64), 0, stream>>>(vbuf, vsTb);
    // 4) attention (overwrites every element of out)
    attn_kernel<<<dim3(64, 32), dim3(256), 0, stream>>>(qbf, kbf, vsTb, out);
}

// Round 10
// 246.412 us; speedup vs baseline: 2.5112x; 1.0134x over previous
//
#include <hip/hip_runtime.h>
#include <hip/hip_bf16.h>
#include <math.h>

#define BB   4
#define SS   2048
#define EE   256
#define HH   8
#define DD   32
#define WW   33
#define KKN  (SS - WW + 1)   // 2016
#define SCALE 0.17677669529663687f  // 1/sqrt(32)
#define FMAX 20.0f           // fixed softmax max: p = exp(s - FMAX); cancels in p/l
#define SCALE2 0.25503486f           // SCALE * log2(e)
#define FM2    28.853900817779268f   // FMAX  * log2(e)

typedef __attribute__((ext_vector_type(8))) short short8v;   // 8 bf16 MFMA A/B frag
typedef __attribute__((ext_vector_type(4))) short short4v;
typedef __attribute__((ext_vector_type(4))) float float4v;   // MFMA C/D frag

// f32 -> bf16 via the compiler's HW convert path (RNE on ROCm>=7).
__device__ __forceinline__ short f2bf(float f) {
    union { __hip_bfloat16 h; short s; } c;
    c.h = __float2bfloat16(f);
    return c.s;
}

// bf16 bits -> f32 (exact)
__device__ __forceinline__ float bf2f(short h) {
    union { unsigned u; float f; } c;
    c.u = ((unsigned)(unsigned short)h) << 16;
    return c.f;
}

// paired convert: one v_cvt_pk_bf16_f32 for two floats (compiler API, no asm)
__device__ __forceinline__ short2 f2bf2(float a, float b) {
    union { __hip_bfloat162 h; short2 s; } c;
    float2 f; f.x = a; f.y = b;
    c.h = __float22bfloat162_rn(f);
    return c.s;
}

#if __has_builtin(__builtin_amdgcn_exp2f)
__device__ __forceinline__ float exp2_fast(float x) { return __builtin_amdgcn_exp2f(x); }
#else
__device__ __forceinline__ float exp2_fast(float x) { return __expf(x * 0.6931471805599453f); }
#endif

// ---------------------------------------------------------------------------
// Kernel 0: W-only hi/lo transposed decomposition (unchanged R17).
// ---------------------------------------------------------------------------
__global__ __launch_bounds__(256) void cvt_kernel(
    const float* __restrict__ Wq, const float* __restrict__ Wk,
    const float* __restrict__ Wv,
    short* __restrict__ wth, short* __restrict__ wtl)
{
    const int t  = threadIdx.x;
    const int bx = blockIdx.x;
    int o   = bx * 2048 + t * 8;
    int mat = o >> 16;
    int rem = o & 65535;
    int n = rem >> 8, k0 = rem & 255;
    const float* W = (mat == 0) ? Wq : (mat == 1) ? Wk : Wv;
    short8v h, l;
#pragma unroll
    for (int j = 0; j < 8; j++) {
        float f = W[(size_t)(k0 + j) * 256 + n];
        short hb = f2bf(f);
        h[j] = hb;
        l[j] = f2bf(f - bf2f(hb));
    }
    *(short8v*)(wth + o) = h;
    *(short8v*)(wtl + o) = l;
}

// ---------------------------------------------------------------------------
// Kernel 1: fused Q/K/V projection, hi/lo bf16 MFMA GEMM (unchanged R17).
// ---------------------------------------------------------------------------
__global__ __launch_bounds__(256) void proj_kernel(
    const float* __restrict__ x,
    const short* __restrict__ wth, const short* __restrict__ wtl,
    const float* __restrict__ bq, const float* __restrict__ bk,
    const float* __restrict__ bv,
    short* __restrict__ qo, short* __restrict__ ko, float* __restrict__ vo)
{
    __shared__ alignas(16) short xsh[64][40];    // x hi tile  [row][k]
    __shared__ alignas(16) short xsl[64][40];    // x lo tile
    __shared__ alignas(16) short wsh[128][40];   // W^T hi tile [col][k]
    __shared__ alignas(16) short wsl[128][40];   // W^T lo tile

    const int t   = threadIdx.x;
    const int r0  = blockIdx.x * 64;
    const int mat = blockIdx.y >> 1;
    const int cb  = blockIdx.y & 1;
    const int lane = t & 63, wv = t >> 6;
    const int quad = lane >> 4, lr = lane & 15;
    const float* bias = (mat == 0) ? bq : (mat == 1) ? bk : bv;
    const size_t wofs = (size_t)(mat * 256 + cb * 128) * 256;
    const short* wthm = wth + wofs;
    const short* wtlm = wtl + wofs;

    float4v acc[8];
#pragma unroll
    for (int ct = 0; ct < 8; ct++) acc[ct] = (float4v){0.f, 0.f, 0.f, 0.f};

    for (int kk = 0; kk < 8; kk++) {
        __syncthreads();
        // stage x: read fp32, split hi/lo in registers (fused cvt)
        {
            int r = t >> 2, c8 = (t & 3) * 8;
            const float* xp = x + (size_t)(r0 + r) * 256 + kk * 32 + c8;
            float4 f0 = *(const float4*)xp;
            float4 f1 = *(const float4*)(xp + 4);
            float f[8] = {f0.x, f0.y, f0.z, f0.w, f1.x, f1.y, f1.z, f1.w};
            short8v h, l;
#pragma unroll
            for (int j = 0; j < 8; j++) {
                short hb = f2bf(f[j]);
                h[j] = hb;
                l[j] = f2bf(f[j] - bf2f(hb));
            }
            *(short8v*)&xsh[r][c8] = h;
            *(short8v*)&xsl[r][c8] = l;
        }
        // stage W^T hi/lo: 128 rows x 32 k = 512 chunks each, 2/thread
#pragma unroll
        for (int i = 0; i < 2; i++) {
            int L = t + i * 256;
            int wr = L >> 2, c8 = (L & 3) * 8;
            size_t go = (size_t)wr * 256 + kk * 32 + c8;
            *(short8v*)&wsh[wr][c8] = *(const short8v*)(wthm + go);
            *(short8v*)&wsl[wr][c8] = *(const short8v*)(wtlm + go);
        }
        __syncthreads();

        const short8v ah = *(const short8v*)&xsh[wv * 16 + lr][quad * 8];
        const short8v al = *(const short8v*)&xsl[wv * 16 + lr][quad * 8];
#pragma unroll
        for (int ct = 0; ct < 8; ct++) {
            const short8v bh_ = *(const short8v*)&wsh[ct * 16 + lr][quad * 8];
            const short8v bl_ = *(const short8v*)&wsl[ct * 16 + lr][quad * 8];
            acc[ct] = __builtin_amdgcn_mfma_f32_16x16x32_bf16(ah, bh_, acc[ct], 0, 0, 0);
            acc[ct] = __builtin_amdgcn_mfma_f32_16x16x32_bf16(ah, bl_, acc[ct], 0, 0, 0);
            acc[ct] = __builtin_amdgcn_mfma_f32_16x16x32_bf16(al, bh_, acc[ct], 0, 0, 0);
        }
    }

    // epilogue: D row = r0 + wv*16 + quad*4 + e; col = cb*128 + ct*16 + lr
    short* op = (mat == 0) ? qo : ko;
#pragma unroll
    for (int ct = 0; ct < 8; ct++) {
        int col = cb * 128 + ct * 16 + lr;
        float bv_ = bias[col];
        int h = col >> 5, d = col & 31;
#pragma unroll
        for (int e = 0; e < 4; e++) {
            int row = r0 + wv * 16 + quad * 4 + e;
            int b_ = row >> 11, s = row & 2047;
            size_t o = (((size_t)(b_ * HH + h)) * SS + s) * DD + d;
            if (mat == 2) vo[o] = acc[ct][e] + bv_;
            else          op[o] = f2bf(acc[ct][e] + bv_);
        }
    }
}

// ---------------------------------------------------------------------------
// Kernel 2: sliding-window sum of V -> transposed bf16 vsT[bh][d][kk].
// ---------------------------------------------------------------------------
__global__ __launch_bounds__(64) void vs_kernel(
    const float* __restrict__ v, short* __restrict__ vsT)
{
    const int t   = threadIdx.x;
    const int d4  = t & 7;
    const int kkb = blockIdx.x * 8 + (t >> 3);
    const int bh  = blockIdx.y;
    if (kkb >= 252) return;
    const int kb0 = kkb * 8;

    const float4* vp = (const float4*)(v + ((size_t)bh * SS + kb0) * DD) + d4;
    float4 rbuf[7];
    float4 acc = {0.f, 0.f, 0.f, 0.f};
#pragma unroll
    for (int w = 0; w < WW; w++) {
        float4 xv = vp[w * 8];
        if (w < 7) rbuf[w] = xv;
        acc.x += xv.x; acc.y += xv.y; acc.z += xv.z; acc.w += xv.w;
    }
    short8v sh[4];
    sh[0][0] = f2bf(acc.x); sh[1][0] = f2bf(acc.y);
    sh[2][0] = f2bf(acc.z); sh[3][0] = f2bf(acc.w);
#pragma unroll
    for (int s = 1; s < 8; s++) {
        float4 sub = rbuf[s - 1];
        float4 add = vp[(s + 32) * 8];
        acc.x += add.x - sub.x; acc.y += add.y - sub.y;
        acc.z += add.z - sub.z; acc.w += add.w - sub.w;
        sh[0][s] = f2bf(acc.x); sh[1][s] = f2bf(acc.y);
        sh[2][s] = f2bf(acc.z); sh[3][s] = f2bf(acc.w);
    }
#pragma unroll
    for (int j = 0; j < 4; j++) {
        short* op = vsT + ((size_t)bh * DD + 4 * d4 + j) * KKN + kb0;
        *(short8v*)op = sh[j];
    }
}

// ---------------------------------------------------------------------------
// Kernel 3: flash attention.
//   R18 changes:
//   - T14 register hoist: vT/Kb stage loads issued at phase-A TOP (held in
//     8 VGPRs across barrier A), LDS writes stay at phase-B top. HBM/L2
//     latency hides under Gram+PV instead of the short score phase.
//     launch_bounds (256,3): VGPR ceiling ~85 (current 64 + 8 staged).
//     R13's spill came from (256,5)'s 48-VGPR cap, not this pattern.
//     Spill tripwire: VGPR < 64 or FETCH >> 38 MB -> revert.
//   - Gram rebalance 7/7/4/4 -> 5/6/6/5 MFMAs/wave: pass 2 now runs on ALL
//     waves, tk = 4+(wv&1), tq windows w0:{0,1} w1:{1,2} w2:{2,3} w3:{3}.
//     Coverage: tk4 needs tq 0..3 = {0,1}u{2,3}; tk5 needs tq 1..3 =
//     {1,2}u{3}; pass 1 (tk=wv, del-filter) unchanged.
// ---------------------------------------------------------------------------
__global__ __launch_bounds__(256, 3) void attn_kernel(
    const short* __restrict__ qg, const short* __restrict__ kg,
    const short* __restrict__ vsTg, float* __restrict__ out)
{
    __shared__ alignas(16) short QbS[64][40];      // Qext; pb union after hoist
    __shared__ alignas(16) short Kb[96][40];       // 96-row K ring (mod 96)
    __shared__ alignas(16) short Gst[96][72];      // bf16 skewed Gram (row 95 = junk)
    __shared__ alignas(16) short vT[32][72];       // single-buffered vs tile [d][ki]
    __shared__ float lrow[32];

    short (*Qb)[40] = QbS;
    short (*pb)[72] = (short (*)[72])QbS;   // 32*72 shorts <= 64*40 ✓ (cols 64..71 junk)

    const int t  = threadIdx.x;
    const int qt = blockIdx.x;
    const int bh = blockIdx.y;
    const int q0 = qt * 32;

    const short* qb   = qg   + (size_t)bh * SS * DD;
    const short* kb   = kg   + (size_t)bh * SS * DD;
    const short* vsTb = vsTg + (size_t)bh * DD * KKN;

    const int lane = t & 63, wv = t >> 6;
    const int quad = lane >> 4, lr = lane & 15;
    const int ptm = wv >> 1, ptn = wv & 1;
    const int jcol = 64 + (t & 7);            // junk column for clamped score writes

    const int qitw  = wv & 1;                 // this wave's qit (score ownership)
    const int tbase = wv >> 1;                // tile parity for this wave pair
    const int qi    = qitw * 16 + lr;         // score row, constant per lane

    const int vd  = t >> 3, vc8 = (t & 7) * 8;   // vT stage coords (kt-invariant)
    const int r2  = t >> 2, c8r = (t & 3) * 8;   // Kb stage coords (kt-invariant)

    // Gram pass-2 tq window (wave-uniform): w0:{0,1} w1:{1,2} w2:{2,3} w3:{3}
    const int tk2   = 4 + (wv & 1);
    const int t2lo  = (wv >> 1) * 2 + (wv & 1);
    const int t2hi  = (wv == 3) ? 3 : (t2lo + 1);

    // ---- zero-init Gst (garbage containment; unwritten cells stay 0) ----
    {
        short8v z = {0, 0, 0, 0, 0, 0, 0, 0};
        short* g = &Gst[0][0];
        for (int i = t; i < 864; i += 256) *(short8v*)(g + 8 * i) = z;
    }

    // ---- initial staging: Qext 64 rows + K rows 0..95 ----
    {
        int gq = q0 - 16 + r2;
        if (gq >= 0 && gq < SS) {
            *(short8v*)&Qb[r2][c8r] = *(const short8v*)(qb + (size_t)gq * DD + c8r);
        } else {
            float4 z = {0.f, 0.f, 0.f, 0.f};
            *(float4*)&Qb[r2][c8r] = z;
        }
        *(short8v*)&Kb[r2][c8r] = *(const short8v*)(kb + (size_t)r2 * DD + c8r);
        if (t < 128)
            *(short8v*)&Kb[64 + r2][c8r] = *(const short8v*)(kb + (size_t)(64 + r2) * DD + c8r);
    }
    if (t < 32) lrow[t] = 0.f;
    __syncthreads();

    // ---- hoist loop-invariant Q B-frags (Qb dead afterwards) ----
    short8v Qf[4];
#pragma unroll
    for (int tq = 0; tq < 4; tq++)
        Qf[tq] = *(const short8v*)&Qb[tq * 16 + lr][quad * 8];

    // ---- banded-ones U-frags for this wave's qit: U[m][qi]=1 iff qi<=m<=qi+32
    short8v Ufw[2];
#pragma unroll
    for (int ch = 0; ch < 2; ch++) {
        short8v u;
#pragma unroll
        for (int j = 0; j < 8; j++) {
            int m = ch * 32 + quad * 8 + j;
            u[j] = (qi <= m && m <= qi + 32) ? (short)0x3F80 : (short)0;
        }
        Ufw[ch] = u;
    }

    float4v acc = {0.f, 0.f, 0.f, 0.f};
    float lsumw = 0.f;
    int k0m = 0;                              // k0 mod 96, cycle {0,64,32}

    for (int kt = 0; kt < 32; kt++) {
        const int k0 = kt * 64;
        // ================= Phase A =================
        // T14 issue-early: global->reg loads (vs tile kt; Kb rows k0+96..159);
        // consumed (LDS write) at phase-B top after barrier A.
        short8v vstage;
        {
            int col = k0 + vc8; if (col > KKN - 8) col = KKN - 8;
            vstage = *(const short8v*)(vsTb + (size_t)vd * KKN + col);
        }
        short8v kstage;
        if (kt < 31) {
            int gp = k0 + 96 + r2;
            int ga = (gp < SS) ? gp : (SS - 1);
            kstage = *(const short8v*)(kb + (size_t)ga * DD + c8r);
        }

        // Gram pass 1: tk = wv, full tq range (del-filtered)
        {
            const int tk = wv;
            int krow = k0m + tk * 16 + lr; if (krow >= 96) krow -= 96;
            const short8v A = *(const short8v*)&Kb[krow][quad * 8];
#pragma unroll
            for (int tq = 0; tq < 4; tq++) {
                const int del = tk - tq;
                if (del < -2 || del > 4) continue;   // dead tile
                float4v c0 = {0.f, 0.f, 0.f, 0.f};
                c0 = __builtin_amdgcn_mfma_f32_16x16x32_bf16(A, Qf[tq], c0, 0, 0, 0);
                const int i   = tq * 16 + lr;
                const int j2b = tk * 16 + quad * 4 - i + 31;
                short* gbase = &Gst[0][i];
                short2 g01 = f2bf2(c0[0], c0[1]);
                short2 g23 = f2bf2(c0[2], c0[3]);
                short gv[4] = {g01.x, g01.y, g23.x, g23.y};
#pragma unroll
                for (int e = 0; e < 4; e++) {
                    int j2 = j2b + e;
                    short* dst = ((unsigned)j2 < 95u) ? (gbase + j2 * 72)
                                                      : (gbase + 95 * 72);
                    *dst = gv[e];
                }
            }
        }
        // Gram pass 2: tk = 4+(wv&1), tq window [t2lo, t2hi] (rebalanced)
        {
            const int tk = tk2;
            int krow = k0m + tk * 16 + lr; if (krow >= 96) krow -= 96;
            const short8v A = *(const short8v*)&Kb[krow][quad * 8];
#pragma unroll
            for (int tq = 0; tq < 4; tq++) {
                if (tq < t2lo || tq > t2hi) continue;
                float4v c0 = {0.f, 0.f, 0.f, 0.f};
                c0 = __builtin_amdgcn_mfma_f32_16x16x32_bf16(A, Qf[tq], c0, 0, 0, 0);
                const int i   = tq * 16 + lr;
                const int j2b = tk * 16 + quad * 4 - i + 31;
                short* gbase = &Gst[0][i];
                short2 g01 = f2bf2(c0[0], c0[1]);
                short2 g23 = f2bf2(c0[2], c0[3]);
                short gv[4] = {g01.x, g01.y, g23.x, g23.y};
#pragma unroll
                for (int e = 0; e < 4; e++) {
                    int j2 = j2b + e;
                    short* dst = ((unsigned)j2 < 95u) ? (gbase + j2 * 72)
                                                      : (gbase + 95 * 72);
                    *dst = gv[e];
                }
            }
        }

        // PV for PREVIOUS iter (k = 64: 2 chained MFMAs); vT holds tile kt-1
        if (kt > 0) {
            const short8v Ap0 = *(const short8v*)&pb[ptm * 16 + lr][quad * 8];
            const short8v Ap1 = *(const short8v*)&pb[ptm * 16 + lr][32 + quad * 8];
            const short8v Bv0 = *(const short8v*)&vT[ptn * 16 + lr][quad * 8];
            const short8v Bv1 = *(const short8v*)&vT[ptn * 16 + lr][32 + quad * 8];
            __builtin_amdgcn_s_setprio(1);
            acc = __builtin_amdgcn_mfma_f32_16x16x32_bf16(Ap0, Bv0, acc, 0, 0, 0);
            acc = __builtin_amdgcn_mfma_f32_16x16x32_bf16(Ap1, Bv1, acc, 0, 0, 0);
            __builtin_amdgcn_s_setprio(0);
        }
        __syncthreads();   // [A] Gst complete; Kb old rows / pb / vT consumed

        // ================= Phase B =================
        // T14 write-late: staged regs -> LDS (loads have had all of phase A)
        *(short8v*)&vT[vd][vc8] = vstage;
        if (kt < 31) {
            int slot = k0m + r2; if (slot >= 96) slot -= 96;
            *(short8v*)&Kb[slot][c8r] = kstage;
        }

        // KKN tail: last tile covers keys 1984..2015 only (ki < 32).
        const unsigned lim = (kt == 31) ? 32u : 64u;
        if (kt == 31) {
            short4v z4 = {0, 0, 0, 0};
            int zr = t >> 3, zc = (t & 7) * 4 + 32;
            *(short4v*)&pb[zr][zc] = z4;
        }

        // scores: 3 (tile,qit)-units per wave; qit = qitw fixed.
        short* prow = &pb[qi][0];
#pragma unroll
        for (int u = 0; u < 3; u++) {
            const int tile = 2 * u + tbase;      // wv<2: {0,2,4}; wv>=2: {1,3,5}
            const int jrow = tile * 16 + lr;
            const short8v A0f = *(const short8v*)&Gst[jrow][quad * 8];
            const short8v A1f = *(const short8v*)&Gst[jrow][32 + quad * 8];
            float4v D = {0.f, 0.f, 0.f, 0.f};
            __builtin_amdgcn_s_setprio(1);
            D = __builtin_amdgcn_mfma_f32_16x16x32_bf16(A0f, Ufw[0], D, 0, 0, 0);
            D = __builtin_amdgcn_mfma_f32_16x16x32_bf16(A1f, Ufw[1], D, 0, 0, 0);
            __builtin_amdgcn_s_setprio(0);
            const int kib = qi + tile * 16 + quad * 4 - 31;
            float p0 = exp2_fast(fmaf(D[0], SCALE2, -FM2));
            float p1 = exp2_fast(fmaf(D[1], SCALE2, -FM2));
            float p2 = exp2_fast(fmaf(D[2], SCALE2, -FM2));
            float p3 = exp2_fast(fmaf(D[3], SCALE2, -FM2));
            short2 c01 = f2bf2(p0, p1);
            short2 c23 = f2bf2(p2, p3);
            float pv[4] = {p0, p1, p2, p3};
            short cv[4] = {c01.x, c01.y, c23.x, c23.y};
#pragma unroll
            for (int e = 0; e < 4; e++) {
                int ki = kib + e;
                bool ok = (unsigned)ki < lim;
                short* dst = ok ? (prow + ki) : (prow + jcol);
                *dst = cv[e];
                lsumw += ok ? pv[e] : 0.f;
            }
        }
        __syncthreads();   // [B] pb ready; vT/Kb staged writes visible
        k0m += 64; if (k0m >= 96) k0m -= 96;
    }

    // ---- final PV (tile 31, staged at B(31)) ----
    {
        const short8v Ap0 = *(const short8v*)&pb[ptm * 16 + lr][quad * 8];
        const short8v Ap1 = *(const short8v*)&pb[ptm * 16 + lr][32 + quad * 8];
        const short8v Bv0 = *(const short8v*)&vT[ptn * 16 + lr][quad * 8];
        const short8v Bv1 = *(const short8v*)&vT[ptn * 16 + lr][32 + quad * 8];
        acc = __builtin_amdgcn_mfma_f32_16x16x32_bf16(Ap0, Bv0, acc, 0, 0, 0);
        acc = __builtin_amdgcn_mfma_f32_16x16x32_bf16(Ap1, Bv1, acc, 0, 0, 0);
    }

    // ---- l reduction: cross-quad shuffle then one atomic per wave ----
    {
        float s = lsumw;
        s += __shfl_xor(s, 16);
        s += __shfl_xor(s, 32);
        if (quad == 0) atomicAdd(&lrow[qitw * 16 + lr], s);
    }
    __syncthreads();

    // ---- epilogue ----
    {
        const int rrow = ptm * 16 + quad * 4;
        const int col  = ptn * 16 + lr;
        const int b_ = bh >> 3, h = bh & 7;
#pragma unroll
        for (int e = 0; e < 4; e++) {
            int s_ = q0 + rrow + e;
            out[((size_t)(b_ * SS + s_)) * EE + h * DD + col] = acc[e] / lrow[rrow + e];
        }
    }
}

// ---------------------------------------------------------------------------
extern "C" void kernel_launch(void* const* d_in, const int* in_sizes, int n_in,
                              void* d_out, int out_size, void* d_ws, size_t ws_size,
                              hipStream_t stream)
{
    (void)in_sizes; (void)n_in; (void)out_size; (void)ws_size;
    const float* x  = (const float*)d_in[0];
    const float* Wq = (const float*)d_in[1];
    const float* bq = (const float*)d_in[2];
    const float* Wk = (const float*)d_in[3];
    const float* bk = (const float*)d_in[4];
    const float* Wv = (const float*)d_in[5];
    const float* bv = (const float*)d_in[6];
    float* out = (float*)d_out;

    const size_t REG = (size_t)BB * HH * SS * DD;   // 2,097,152
    short* qbf   = (short*)d_ws;
    short* kbf   = qbf + REG;
    float* vbuf  = (float*)(kbf + REG);
    short* vsTb  = (short*)(vbuf + REG);            // 32*32*2016 shorts

    // W^T hi/lo scratch (768 KB) lives in `out`; attn fully overwrites out.
    short* wth = (short*)out;
    short* wtl = wth + 3 * 256 * 256;

    // 1) hi/lo bf16 decomposition of W^T (q, k, v)
    cvt_kernel<<<dim3(96), dim3(256), 0, stream>>>(Wq, Wk, Wv, wth, wtl);
    // 2) fused Q/K/V projection via hi/lo bf16 MFMA (x split in-register)
    proj_kernel<<<dim3(128, 6), dim3(256), 0, stream>>>(x, wth, wtl,
                                                        bq, bk, bv,
                                                        qbf, kbf, vbuf);
    // 3) window sums of V
    vs_kernel<<<dim3(32, 32), dim3(64), 0, stream>>>(vbuf, vsTb);
    // 4) attention (overwrites every element of out)
    attn_kernel<<<dim3(64, 32), dim3(256), 0, stream>>>(qbf, kbf, vsTb, out);
}